// Round 3
// baseline (7350.643 us; speedup 1.0000x reference)
//
#include <hip/hip_runtime.h>
#include <math.h>

#define BB 256
#define TIN 32
#define TOUT 29
#define VDEC 72
#define EDIM 256
#define HDIM 256
#define DD 6
#define BH (BB*HDIM)
#define NB 256

typedef unsigned short u16;
typedef unsigned int u32;
typedef __bf16 bf16x8 __attribute__((ext_vector_type(8)));
typedef float f32x4 __attribute__((ext_vector_type(4)));
typedef u16 u16x8 __attribute__((ext_vector_type(8)));

__device__ __forceinline__ float sigmf(float x){ return 1.0f/(1.0f+expf(-x)); }
__device__ __forceinline__ u16 f2bf(float f){
  u32 u = __builtin_bit_cast(u32, f);
  u32 r = (u + 0x7fffu + ((u>>16)&1u)) >> 16;   // RNE; inputs finite
  return (u16)r;
}
__device__ __forceinline__ float bf2f(u16 s){
  u32 u = ((u32)s)<<16; return __builtin_bit_cast(float, u);
}
__device__ __forceinline__ bf16x8 ldbf8(const u16* p){
  u16x8 t = *(const u16x8*)p; return __builtin_bit_cast(bf16x8, t);
}
__device__ __forceinline__ f32x4 mfma16(bf16x8 a, bf16x8 b, f32x4 c){
  return __builtin_amdgcn_mfma_f32_16x16x32_bf16(a, b, c, 0, 0, 0);
}

// ==================== setup kernels ====================

__global__ void fill_zero_u32(u32* __restrict__ p, int n){
  int i = blockIdx.x*256 + threadIdx.x;
  if (i < n) p[i] = 0u;
}

__global__ void init_out_kernel(float* __restrict__ out, int n){
  int i = blockIdx.x*256 + threadIdx.x;
  if (i >= n) return;
  float v = 0.0f;
  if (i < BB*VDEC && (i % VDEC) == 1) v = 1.0f;   // pred0 one-hot
  out[i] = v;
}

// bias2d[p][m][g] = (sum_l W2[m,l]) * b1[g] + b2[m]   (p: 0=a, 1=h, 2=c)
__global__ void bias2d_kernel(const float* __restrict__ W2a, const float* __restrict__ b1a, const float* __restrict__ b2a,
                              const float* __restrict__ W2h, const float* __restrict__ b1h, const float* __restrict__ b2h,
                              const float* __restrict__ W2c, const float* __restrict__ b1c, const float* __restrict__ b2c,
                              float* __restrict__ outp){
  int g = threadIdx.x;
  const float* W2[3] = {W2a, W2h, W2c};
  const float* b1[3] = {b1a, b1h, b1c};
  const float* b2[3] = {b2a, b2h, b2c};
  for (int p = 0; p < 3; p++)
    for (int m = 0; m < 6; m++){
      float s = 0.f;
      for (int l = 0; l < 6; l++) s += W2[p][m*6+l];
      outp[p*1536 + m*256 + g] = s * b1[p][g] + b2[p][m];
    }
}

__global__ void embed_enc_kernel(const int* __restrict__ input, const float* __restrict__ enc_emb,
                                 u16* __restrict__ x_emb){
  int i = blockIdx.x*256 + threadIdx.x;       // TIN*BB*EDIM threads
  int e = i & 255, b = (i >> 8) & 255, t = i >> 16;
  x_emb[i] = f2bf(enc_emb[(size_t)input[b*TIN + t]*EDIM + e]);
}

// pack fp32 weights -> bf16, row-permuted: dst row' = (d,ht,q,hh) -> g = q*256+ht*16+hh
__global__ void pack_w_kernel(const float* __restrict__ Wih, const float* __restrict__ Whh,
                              u16* __restrict__ dst, int K1, int K){
  int k = blockIdx.x*256 + threadIdx.x;
  int row = blockIdx.y;
  int d = row >> 10, rr = row & 1023;
  int g = ((rr>>4)&3)*256 + (rr>>6)*16 + (rr&15);
  float v;
  if (k < K1) v = Wih[((size_t)d*1024 + g)*K1 + k];
  else        v = Whh[((size_t)d*1024 + g)*256 + (k - K1)];
  dst[(size_t)row*K + k] = f2bf(v);
}

// bf16 copies of the three 256x256 W1s
__global__ void pack3_kernel(const float* __restrict__ a, const float* __restrict__ b, const float* __restrict__ c,
                             u16* __restrict__ oa, u16* __restrict__ ob, u16* __restrict__ oc){
  int i = blockIdx.x*256 + threadIdx.x;   // 65536
  oa[i] = f2bf(a[i]); ob[i] = f2bf(b[i]); oc[i] = f2bf(c[i]);
}

// composite decoder stage-0 weights: Wc[g][j] = sum_e Wih0[d][g][e]*attn_W[e][j] (j<512),
// then Whh cols; packed row-permuted; also b0'[d][g] = dec_b0[d][g] + Wih0[d][g]·attn_b
__global__ __launch_bounds__(256) void comp_w_kernel(
    const float* __restrict__ Wih0, const float* __restrict__ Whh0,
    const float* __restrict__ attn_W, const float* __restrict__ attn_b,
    const float* __restrict__ dec_b0, u16* __restrict__ wpk, float* __restrict__ b0p){
  __shared__ float sw[8][256];
  __shared__ float red[256];
  int tid = threadIdx.x;
  int rbase = blockIdx.x*8;
  int gs[8], ds[8];
  for (int r = 0; r < 8; r++){
    int row = rbase + r;
    int d = row >> 10, rr = row & 1023;
    int g = ((rr>>4)&3)*256 + (rr>>6)*16 + (rr&15);
    gs[r] = g; ds[r] = d;
    sw[r][tid] = Wih0[((size_t)d*1024 + g)*256 + tid];
  }
  __syncthreads();
  float a0[8], a1[8];
  #pragma unroll
  for (int r = 0; r < 8; r++){ a0[r]=0.f; a1[r]=0.f; }
  for (int e = 0; e < 256; e++){
    float w0 = attn_W[(size_t)e*512 + tid];
    float w1 = attn_W[(size_t)e*512 + 256 + tid];
    #pragma unroll
    for (int r = 0; r < 8; r++){ float s = sw[r][e]; a0[r] += s*w0; a1[r] += s*w1; }
  }
  for (int r = 0; r < 8; r++){
    int row = rbase + r;
    wpk[(size_t)row*768 + tid]       = f2bf(a0[r]);
    wpk[(size_t)row*768 + 256 + tid] = f2bf(a1[r]);
    wpk[(size_t)row*768 + 512 + tid] = f2bf(Whh0[((size_t)ds[r]*1024 + gs[r])*256 + tid]);
  }
  for (int r = 0; r < 8; r++){
    red[tid] = sw[r][tid]*attn_b[tid];
    __syncthreads();
    for (int s2 = 128; s2 > 0; s2 >>= 1){ if (tid < s2) red[tid] += red[tid+s2]; __syncthreads(); }
    if (tid == 0) b0p[ds[r]*1024 + gs[r]] = dec_b0[(size_t)ds[r]*1024 + gs[r]] + red[0];
    __syncthreads();
  }
}

// ==================== mega kernel ====================

__device__ __forceinline__ void gbar(int* cnt, int& ep){
  __syncthreads();
  ep++;
  if (threadIdx.x == 0){
    __threadfence();
    __hip_atomic_fetch_add(cnt, 1, __ATOMIC_RELEASE, __HIP_MEMORY_SCOPE_AGENT);
    int target = NB * ep;
    while (__hip_atomic_load(cnt, __ATOMIC_ACQUIRE, __HIP_MEMORY_SCOPE_AGENT) < target)
      __builtin_amdgcn_s_sleep(2);
    __threadfence();
  }
  __syncthreads();
}

// fused LSTM stage unit: block bid -> (m = bid>>5, d = (bid>>4)&1, ht = bid&15)
__device__ __forceinline__ void stage_unit(
    const u16* __restrict__ inp, int lda, int K1,
    const u16* __restrict__ Wpk, const float* __restrict__ bias_l,
    const u16* __restrict__ hR, u16* __restrict__ hW,
    float* __restrict__ cBuf, u16* __restrict__ inp_out,
    u16* __restrict__ h_all_t, int l, char* smem){
  u16 (*As)[72] = (u16(*)[72])smem;                       // 32x72 = 4608 B
  u16 (*Ws)[72] = (u16(*)[72])(smem + 4608);              // 64x72 = 9216 B
  float (*Gt)[32][17] = (float(*)[32][17])(smem + 13824); // 4x32x17x4 = 8704 B
  int tid = threadIdx.x;
  int bid = blockIdx.x;
  int m_base = (bid >> 5)*32;
  int dht = bid & 31;
  int d = dht >> 4, ht = dht & 15;
  int idx = 2*l + d;
  int K = K1 + 256;
  const u16* Wblk = Wpk + (size_t)(dht*64)*K;
  const u16* A2 = hR + (size_t)idx*BH;
  int q = tid >> 6, lane = tid & 63;
  int ar = tid >> 3, kp = (tid & 7)*8;
  f32x4 acc0 = {0.f,0.f,0.f,0.f}, acc1 = {0.f,0.f,0.f,0.f};
  for (int c0 = 0; c0 < K; c0 += 64){
    int col = c0 + kp;
    const u16* ap = (col < K1) ? inp + (size_t)(m_base+ar)*lda + col
                               : A2  + (size_t)(m_base+ar)*HDIM + (col - K1);
    uint4 av  = *(const uint4*)ap;
    uint4 wv0 = *(const uint4*)(Wblk + (size_t)ar*K + col);
    uint4 wv1 = *(const uint4*)(Wblk + (size_t)(ar+32)*K + col);
    __syncthreads();
    *(uint4*)&As[ar][kp] = av;
    *(uint4*)&Ws[ar][kp] = wv0;
    *(uint4*)&Ws[ar+32][kp] = wv1;
    __syncthreads();
    #pragma unroll
    for (int kh = 0; kh < 2; kh++){
      int kb = kh*32 + (lane>>4)*8;
      bf16x8 a0v = ldbf8(&As[lane & 15][kb]);
      bf16x8 a1v = ldbf8(&As[16 + (lane & 15)][kb]);
      bf16x8 bq  = ldbf8(&Ws[q*16 + (lane & 15)][kb]);
      acc0 = mfma16(a0v, bq, acc0);
      acc1 = mfma16(a1v, bq, acc1);
    }
  }
  int hh = lane & 15, rq = lane >> 4;
  #pragma unroll
  for (int r = 0; r < 4; r++){
    Gt[q][rq*4 + r][hh]      = acc0[r];
    Gt[q][16 + rq*4 + r][hh] = acc1[r];
  }
  __syncthreads();
  const float* bias = bias_l + d*1024;
  #pragma unroll
  for (int it = 0; it < 2; it++){
    int id = tid + it*256;
    int bb = id >> 4, h2 = id & 15;
    int b = m_base + bb, h = ht*16 + h2;
    float iv = Gt[0][bb][h2] + bias[h];
    float fv = Gt[1][bb][h2] + bias[256 + h];
    float gv = Gt[2][bb][h2] + bias[512 + h];
    float ov = Gt[3][bb][h2] + bias[768 + h];
    size_t off = (size_t)idx*BH + (size_t)b*HDIM + h;
    float cold = cBuf[off];
    float cc = sigmf(fv)*cold + sigmf(iv)*tanhf(gv);
    float hv = sigmf(ov)*tanhf(cc);
    cBuf[off] = cc;
    u16 hb = f2bf(hv);
    hW[off] = hb;
    inp_out[(size_t)b*512 + d*HDIM + h] = hb;
    if (h_all_t) h_all_t[off] = hb;
  }
}

// generic bf16 GEMM unit: C[32 rows x 64 cols] = A[rows,256] @ W[n,256]^T + bias2d
// mode 0: bf16 row-major out; 1: fp32 row-major out; 2: eo2 scatter [b][m][t][n]
__device__ __forceinline__ void gemm_unit(
    const u16* __restrict__ A, const u16* __restrict__ W,
    const float* __restrict__ bias2, int r0, int n0, int mode,
    u16* __restrict__ outb, float* __restrict__ outf, char* smem){
  u16 (*As)[72] = (u16(*)[72])smem;
  u16 (*Ws)[72] = (u16(*)[72])(smem + 4608);
  int tid = threadIdx.x;
  int q = tid >> 6, lane = tid & 63;
  int ar = tid >> 3, kp = (tid & 7)*8;
  f32x4 acc0 = {0.f,0.f,0.f,0.f}, acc1 = {0.f,0.f,0.f,0.f};
  for (int c0 = 0; c0 < 256; c0 += 64){
    int col = c0 + kp;
    uint4 av  = *(const uint4*)(A + (size_t)(r0+ar)*256 + col);
    uint4 wv0 = *(const uint4*)(W + (size_t)(n0+ar)*256 + col);
    uint4 wv1 = *(const uint4*)(W + (size_t)(n0+ar+32)*256 + col);
    __syncthreads();
    *(uint4*)&As[ar][kp] = av;
    *(uint4*)&Ws[ar][kp] = wv0;
    *(uint4*)&Ws[ar+32][kp] = wv1;
    __syncthreads();
    #pragma unroll
    for (int kh = 0; kh < 2; kh++){
      int kb = kh*32 + (lane>>4)*8;
      bf16x8 a0v = ldbf8(&As[lane & 15][kb]);
      bf16x8 a1v = ldbf8(&As[16 + (lane & 15)][kb]);
      bf16x8 bq  = ldbf8(&Ws[q*16 + (lane & 15)][kb]);
      acc0 = mfma16(a0v, bq, acc0);
      acc1 = mfma16(a1v, bq, acc1);
    }
  }
  int hh = lane & 15, rq = lane >> 4;
  int n = n0 + q*16 + hh;
  #pragma unroll
  for (int r = 0; r < 4; r++){
    #pragma unroll
    for (int half = 0; half < 2; half++){
      int row = r0 + half*16 + rq*4 + r;
      float v = (half ? acc1[r] : acc0[r]) + bias2[((row>>8)%6)*256 + n];
      if (mode == 0)      outb[(size_t)row*256 + n] = f2bf(v);
      else if (mode == 1) outf[(size_t)row*256 + n] = v;
      else {
        int b = row & 255, mm = (row>>8)%6, t = row/1536;
        outb[(((size_t)(b*6 + mm)*32 + t)*256) + n] = f2bf(v);
      }
    }
  }
}

__device__ __forceinline__ void attn_unit(const u16* __restrict__ hR, const u16* __restrict__ eo2,
                                          u16* __restrict__ embctx, const int* __restrict__ tf,
                                          float* __restrict__ attn_out, int step, int b){
  int hc = threadIdx.x;
  bool wa = (tf[0] == 0);
  float acc = 0.f;
  for (int d = 0; d < 6; d++){
    float hv = bf2f(hR[(size_t)d*BH + (size_t)b*256 + hc]);
    const u16* base = eo2 + ((size_t)(b*6 + d)*32)*256 + hc;
    float se = 0.f, ac = 0.f;
    #pragma unroll 8
    for (int t = 0; t < TIN; t++){
      float ev = bf2f(base[t*256]);
      float e = expf(hv*ev);
      se += e; ac += e*ev;
    }
    acc += ac/se;
    if (wa){
      float inv = 1.f/se;
      for (int t = 0; t < TIN; t++){
        float ev = bf2f(base[t*256]);
        atomicAdd(&attn_out[(((size_t)(step+1)*TIN + t)*DD + d)*BB + b], expf(hv*ev)*inv);
      }
    }
  }
  embctx[(size_t)b*512 + 256 + hc] = f2bf(acc*(1.0f/6.0f));
}

__device__ __forceinline__ void fc_unit(const u16* __restrict__ top, const float* __restrict__ fc_W,
                                        const float* __restrict__ fc_b, float* __restrict__ out,
                                        int slot, int b, char* smem){
  float* s  = (float*)smem;          // 512 f
  float* lg = (float*)(smem + 2048); // 72 f
  int tid = threadIdx.x;
  s[tid]       = bf2f(top[(size_t)b*512 + tid]);
  s[tid + 256] = bf2f(top[(size_t)b*512 + 256 + tid]);
  __syncthreads();
  if (tid < VDEC){
    float a = fc_b[tid];
    for (int k = 0; k < 512; k++) a += s[k]*fc_W[(size_t)tid*512 + k];
    out[((size_t)slot*256 + b)*VDEC + tid] = a;
    lg[tid] = a;
  }
  __syncthreads();
}

__device__ __forceinline__ void emb_unit(int i, const int* __restrict__ tf, const int* __restrict__ target,
                                         const float* __restrict__ lg, const float* __restrict__ dec_emb,
                                         u16* __restrict__ embctx, int b, char* smem){
  int* tokp = (int*)(smem + 2368);
  int tid = threadIdx.x;
  if (tid == 0){
    int tok;
    if (tf[0]) tok = target[b*TOUT + i];
    else if (i == 0) tok = 1;
    else {
      tok = 0; float bv = lg[0];
      for (int v = 1; v < VDEC; v++){ float x = lg[v]; if (x > bv){ bv = x; tok = v; } }
    }
    *tokp = tok;
  }
  __syncthreads();
  int tok = *tokp;
  embctx[(size_t)b*512 + tid] = f2bf(dec_emb[(size_t)tok*EDIM + tid]);
  __syncthreads();
}

struct MegaArgs {
  const int *target, *tf;
  const float *enc_b, *dec_b, *fc_W, *fc_b, *dec_emb;
  const float *lin_h_W2, *lin_c_W2, *lin_a_W2;
  const u16 *x_emb, *wp_e0, *wp_e1, *wp_e2, *wp_dc0, *wp_d1, *wp_d2;
  const float *dc_b0p;
  const u16 *w1h, *w1c, *w1a;
  const float *bias2d;
  u16 *h_all_bf, *enc_hA, *enc_hB;
  float *enc_c;
  u16 *tmp6hc;
  u16 *eo2, *dec_hA, *dec_hB;
  float *dec_c;
  u16 *bufA, *bufB, *bufC, *embctx;
  float *out, *attn_out;
  int *cnt;
};

__global__ __launch_bounds__(256, 1) void mega_kernel(MegaArgs a){
  __shared__ __align__(16) char smem[23040];
  int ep = 0;
  int bid = blockIdx.x, tid = threadIdx.x;
  // -------- encoder: 32 steps x 3 stages --------
  for (int t = 0; t < TIN; t++){
    const u16* hR = (t & 1) ? a.enc_hB : a.enc_hA;
    u16* hW = (t & 1) ? a.enc_hA : a.enc_hB;
    u16* hat = a.h_all_bf + (size_t)t*6*BH;
    stage_unit(a.x_emb + (size_t)t*BB*256, 256, 256, a.wp_e0, a.enc_b,        hR, hW, a.enc_c, a.bufA, hat, 0, smem);
    gbar(a.cnt, ep);
    stage_unit(a.bufA, 512, 512, a.wp_e1, a.enc_b + 2048, hR, hW, a.enc_c, a.bufB, hat, 1, smem);
    gbar(a.cnt, ep);
    stage_unit(a.bufB, 512, 512, a.wp_e2, a.enc_b + 4096, hR, hW, a.enc_c, a.bufA, hat, 2, smem);
    gbar(a.cnt, ep);
  }
  // -------- B1: W2-mixes (each thread owns (b=bid, h=tid)) --------
  {
    float* sW2 = (float*)smem;    // 108 f: [0..36) h, [36..72) c, [72..108) a
    if (tid < 108){
      int p = tid/36, j = tid%36;
      const float* src = (p==0)? a.lin_h_W2 : (p==1 ? a.lin_c_W2 : a.lin_a_W2);
      sW2[tid] = src[j];
    }
    __syncthreads();
    int b = bid, h = tid;
    float v[6];
    #pragma unroll
    for (int l2 = 0; l2 < 6; l2++) v[l2] = bf2f(a.h_all_bf[((size_t)(31*6 + l2)*BB + b)*256 + h]);
    #pragma unroll
    for (int m = 0; m < 6; m++){
      float o = 0.f;
      #pragma unroll
      for (int l2 = 0; l2 < 6; l2++) o += sW2[m*6+l2]*v[l2];
      a.tmp6hc[((size_t)(m*256 + b))*256 + h] = f2bf(o);
    }
    #pragma unroll
    for (int l2 = 0; l2 < 6; l2++) v[l2] = a.enc_c[(size_t)l2*BH + (size_t)b*256 + h];
    #pragma unroll
    for (int m = 0; m < 6; m++){
      float o = 0.f;
      #pragma unroll
      for (int l2 = 0; l2 < 6; l2++) o += sW2[36 + m*6+l2]*v[l2];
      a.tmp6hc[((size_t)(1536 + m*256 + b))*256 + h] = f2bf(o);
    }
    for (int t = 0; t < TIN; t++){
      #pragma unroll
      for (int l2 = 0; l2 < 6; l2++) v[l2] = bf2f(a.h_all_bf[((size_t)(t*6 + l2)*BB + b)*256 + h]);
      #pragma unroll
      for (int m = 0; m < 6; m++){
        float o = 0.f;
        #pragma unroll
        for (int l2 = 0; l2 < 6; l2++) o += sW2[72 + m*6+l2]*v[l2];
        a.h_all_bf[((size_t)(t*6 + m)*BB + b)*256 + h] = f2bf(o);
      }
    }
  }
  gbar(a.cnt, ep);
  // -------- B2: bridge GEMMs + attention projection (units over blocks) --------
  for (int u = bid; u < 6528; u += NB){
    if (u < 192){
      int r0 = (u>>2)*32, n0 = (u&3)*64;
      gemm_unit(a.tmp6hc, a.w1h, a.bias2d + 1536, r0, n0, 0, a.dec_hA, nullptr, smem);
    } else if (u < 384){
      int v2 = u - 192;
      int r0 = (v2>>2)*32, n0 = (v2&3)*64;
      gemm_unit(a.tmp6hc + (size_t)1536*256, a.w1c, a.bias2d + 3072, r0, n0, 1, nullptr, a.dec_c, smem);
    } else {
      int at = u - 384;
      int r0 = (at>>2)*32, n0 = (at&3)*64;
      gemm_unit(a.h_all_bf, a.w1a, a.bias2d, r0, n0, 2, a.eo2, nullptr, smem);
    }
  }
  gbar(a.cnt, ep);
  // -------- decoder: 28 steps x 4 phases --------
  for (int i = 0; i < TOUT-1; i++){
    const u16* hR = (i & 1) ? a.dec_hB : a.dec_hA;
    u16* hW = (i & 1) ? a.dec_hA : a.dec_hB;
    attn_unit(hR, a.eo2, a.embctx, a.tf, a.attn_out, i, bid);
    if (i > 0) fc_unit(a.bufC, a.fc_W, a.fc_b, a.out, i, bid, smem);
    emb_unit(i, a.tf, a.target, (const float*)(smem + 2048), a.dec_emb, a.embctx, bid, smem);
    gbar(a.cnt, ep);
    stage_unit(a.embctx, 512, 512, a.wp_dc0, a.dc_b0p,       hR, hW, a.dec_c, a.bufA, nullptr, 0, smem);
    gbar(a.cnt, ep);
    stage_unit(a.bufA, 512, 512, a.wp_d1, a.dec_b + 2048, hR, hW, a.dec_c, a.bufB, nullptr, 1, smem);
    gbar(a.cnt, ep);
    stage_unit(a.bufB, 512, 512, a.wp_d2, a.dec_b + 4096, hR, hW, a.dec_c, a.bufC, nullptr, 2, smem);
    gbar(a.cnt, ep);
  }
  fc_unit(a.bufC, a.fc_W, a.fc_b, a.out, TOUT-1, bid, smem);
}

// =====================================================================

extern "C" void kernel_launch(void* const* d_in, const int* in_sizes, int n_in,
                              void* d_out, int out_size, void* d_ws, size_t ws_size,
                              hipStream_t stream){
  (void)in_sizes; (void)n_in; (void)out_size; (void)ws_size;
  const int*   input    = (const int*)d_in[0];
  const int*   target   = (const int*)d_in[1];
  const int*   tf       = (const int*)d_in[2];
  const float* enc_emb  = (const float*)d_in[3];
  const float* dec_emb  = (const float*)d_in[4];
  const float* enc_Wih0 = (const float*)d_in[5];
  const float* enc_Wih1 = (const float*)d_in[6];
  const float* enc_Whh  = (const float*)d_in[7];
  const float* enc_b    = (const float*)d_in[8];
  const float* dec_Wih0 = (const float*)d_in[9];
  const float* dec_Wih1 = (const float*)d_in[10];
  const float* dec_Whh  = (const float*)d_in[11];
  const float* dec_b    = (const float*)d_in[12];
  const float* lin_h_W1 = (const float*)d_in[13];
  const float* lin_h_b1 = (const float*)d_in[14];
  const float* lin_h_W2 = (const float*)d_in[15];
  const float* lin_h_b2 = (const float*)d_in[16];
  const float* lin_c_W1 = (const float*)d_in[17];
  const float* lin_c_b1 = (const float*)d_in[18];
  const float* lin_c_W2 = (const float*)d_in[19];
  const float* lin_c_b2 = (const float*)d_in[20];
  const float* lin_a_W1 = (const float*)d_in[21];
  const float* lin_a_b1 = (const float*)d_in[22];
  const float* lin_a_W2 = (const float*)d_in[23];
  const float* lin_a_b2 = (const float*)d_in[24];
  const float* attn_W   = (const float*)d_in[25];
  const float* attn_b   = (const float*)d_in[26];
  const float* fc_W     = (const float*)d_in[27];
  const float* fc_b     = (const float*)d_in[28];
  float* out = (float*)d_out;

  char* base = (char*)d_ws;
  size_t off = 0;
  auto alloc = [&](size_t bytes)->char*{
    char* p = base + off; off += (bytes + 255) & ~(size_t)255; return p;
  };
  // zero block: [cnt pad | enc_hA bf16 | enc_c fp32] contiguous
  int*   cnt    = (int*)alloc(256);
  u16*   enc_hA = (u16*)alloc(sizeof(u16)*(size_t)DD*BH);
  float* enc_c  = (float*)alloc(sizeof(float)*(size_t)DD*BH);
  size_t zero_u32 = (256 + sizeof(u16)*(size_t)DD*BH + sizeof(float)*(size_t)DD*BH)/4;

  u16*   enc_hB = (u16*)alloc(sizeof(u16)*(size_t)DD*BH);
  u16*   dec_hA = (u16*)alloc(sizeof(u16)*(size_t)DD*BH);
  u16*   dec_hB = (u16*)alloc(sizeof(u16)*(size_t)DD*BH);
  float* dec_c  = (float*)alloc(sizeof(float)*(size_t)DD*BH);
  u16*   tmp6hc = (u16*)alloc(sizeof(u16)*(size_t)2*1536*256);
  u16*   h_all  = (u16*)alloc(sizeof(u16)*(size_t)TIN*DD*BH);
  u16*   eo2    = (u16*)alloc(sizeof(u16)*(size_t)TIN*DD*BH);
  u16*   x_emb  = (u16*)alloc(sizeof(u16)*(size_t)TIN*BB*EDIM);
  u16*   bufA   = (u16*)alloc(sizeof(u16)*(size_t)BB*512);
  u16*   bufB   = (u16*)alloc(sizeof(u16)*(size_t)BB*512);
  u16*   bufC   = (u16*)alloc(sizeof(u16)*(size_t)BB*512);
  u16*   embctx = (u16*)alloc(sizeof(u16)*(size_t)BB*512);
  float* bias2d = (float*)alloc(sizeof(float)*3*6*256);
  float* dc_b0p = (float*)alloc(sizeof(float)*2048);
  u16*   w1h    = (u16*)alloc(sizeof(u16)*65536);
  u16*   w1c    = (u16*)alloc(sizeof(u16)*65536);
  u16*   w1a    = (u16*)alloc(sizeof(u16)*65536);
  u16*   wp_e0  = (u16*)alloc(sizeof(u16)*(size_t)2048*512);
  u16*   wp_e1  = (u16*)alloc(sizeof(u16)*(size_t)2048*768);
  u16*   wp_e2  = (u16*)alloc(sizeof(u16)*(size_t)2048*768);
  u16*   wp_dc0 = (u16*)alloc(sizeof(u16)*(size_t)2048*768);
  u16*   wp_d1  = (u16*)alloc(sizeof(u16)*(size_t)2048*768);
  u16*   wp_d2  = (u16*)alloc(sizeof(u16)*(size_t)2048*768);

  const int outn = TOUT*BB*VDEC + TOUT*TIN*DD*BB;
  init_out_kernel<<<(outn+255)/256, 256, 0, stream>>>(out, outn);
  fill_zero_u32<<<((int)zero_u32+255)/256, 256, 0, stream>>>((u32*)cnt, (int)zero_u32);
  bias2d_kernel<<<1, 256, 0, stream>>>(lin_a_W2, lin_a_b1, lin_a_b2,
                                       lin_h_W2, lin_h_b1, lin_h_b2,
                                       lin_c_W2, lin_c_b1, lin_c_b2, bias2d);
  embed_enc_kernel<<<(TIN*BB*EDIM)/256, 256, 0, stream>>>(input, enc_emb, x_emb);
  pack_w_kernel<<<dim3(2,2048), 256, 0, stream>>>(enc_Wih0, enc_Whh,                       wp_e0, 256, 512);
  pack_w_kernel<<<dim3(3,2048), 256, 0, stream>>>(enc_Wih1, enc_Whh + 2*1024*256,          wp_e1, 512, 768);
  pack_w_kernel<<<dim3(3,2048), 256, 0, stream>>>(enc_Wih1 + (size_t)2*1024*512, enc_Whh + 4*1024*256, wp_e2, 512, 768);
  pack_w_kernel<<<dim3(3,2048), 256, 0, stream>>>(dec_Wih1, dec_Whh + 2*1024*256,          wp_d1, 512, 768);
  pack_w_kernel<<<dim3(3,2048), 256, 0, stream>>>(dec_Wih1 + (size_t)2*1024*512, dec_Whh + 4*1024*256, wp_d2, 512, 768);
  pack3_kernel<<<256, 256, 0, stream>>>(lin_h_W1, lin_c_W1, lin_a_W1, w1h, w1c, w1a);
  comp_w_kernel<<<256, 256, 0, stream>>>(dec_Wih0, dec_Whh, attn_W, attn_b, dec_b, wp_dc0, dc_b0p);

  MegaArgs a;
  a.target = target; a.tf = tf;
  a.enc_b = enc_b; a.dec_b = dec_b; a.fc_W = fc_W; a.fc_b = fc_b; a.dec_emb = dec_emb;
  a.lin_h_W2 = lin_h_W2; a.lin_c_W2 = lin_c_W2; a.lin_a_W2 = lin_a_W2;
  a.x_emb = x_emb; a.wp_e0 = wp_e0; a.wp_e1 = wp_e1; a.wp_e2 = wp_e2;
  a.wp_dc0 = wp_dc0; a.wp_d1 = wp_d1; a.wp_d2 = wp_d2;
  a.dc_b0p = dc_b0p; a.w1h = w1h; a.w1c = w1c; a.w1a = w1a; a.bias2d = bias2d;
  a.h_all_bf = h_all; a.enc_hA = enc_hA; a.enc_hB = enc_hB; a.enc_c = enc_c;
  a.tmp6hc = tmp6hc; a.eo2 = eo2; a.dec_hA = dec_hA; a.dec_hB = dec_hB; a.dec_c = dec_c;
  a.bufA = bufA; a.bufB = bufB; a.bufC = bufC; a.embctx = embctx;
  a.out = out; a.attn_out = out + (size_t)TOUT*BB*VDEC; a.cnt = cnt;
  mega_kernel<<<NB, 256, 0, stream>>>(a);
}

// Round 4
// 5740.738 us; speedup vs baseline: 1.2804x; 1.2804x over previous
//
#include <hip/hip_runtime.h>
#include <math.h>

#define BB 256
#define TIN 32
#define TOUT 29
#define VDEC 72
#define EDIM 256
#define HDIM 256
#define DD 6
#define BH (BB*HDIM)
#define NB 256

typedef unsigned short u16;
typedef unsigned int u32;
typedef __bf16 bf16x8 __attribute__((ext_vector_type(8)));
typedef float f32x4 __attribute__((ext_vector_type(4)));
typedef u16 u16x8 __attribute__((ext_vector_type(8)));

__device__ __forceinline__ float sigmf(float x){ return 1.0f/(1.0f+expf(-x)); }
__device__ __forceinline__ u16 f2bf(float f){
  u32 u = __builtin_bit_cast(u32, f);
  u32 r = (u + 0x7fffu + ((u>>16)&1u)) >> 16;   // RNE; inputs finite
  return (u16)r;
}
__device__ __forceinline__ float bf2f(u16 s){
  u32 u = ((u32)s)<<16; return __builtin_bit_cast(float, u);
}
__device__ __forceinline__ bf16x8 ldbf8(const u16* p){
  u16x8 t = *(const u16x8*)p; return __builtin_bit_cast(bf16x8, t);
}
__device__ __forceinline__ f32x4 mfma16(bf16x8 a, bf16x8 b, f32x4 c){
  return __builtin_amdgcn_mfma_f32_16x16x32_bf16(a, b, c, 0, 0, 0);
}

// ==================== setup kernels ====================

__global__ void fill_zero_u32(u32* __restrict__ p, int n){
  int i = blockIdx.x*256 + threadIdx.x;
  if (i < n) p[i] = 0u;
}

__global__ void init_out_kernel(float* __restrict__ out, int n){
  int i = blockIdx.x*256 + threadIdx.x;
  if (i >= n) return;
  float v = 0.0f;
  if (i < BB*VDEC && (i % VDEC) == 1) v = 1.0f;   // pred0 one-hot
  out[i] = v;
}

// bias2d[p][m][g] = (sum_l W2[m,l]) * b1[g] + b2[m]   (p: 0=a, 1=h, 2=c)
__global__ void bias2d_kernel(const float* __restrict__ W2a, const float* __restrict__ b1a, const float* __restrict__ b2a,
                              const float* __restrict__ W2h, const float* __restrict__ b1h, const float* __restrict__ b2h,
                              const float* __restrict__ W2c, const float* __restrict__ b1c, const float* __restrict__ b2c,
                              float* __restrict__ outp){
  int g = threadIdx.x;
  const float* W2[3] = {W2a, W2h, W2c};
  const float* b1[3] = {b1a, b1h, b1c};
  const float* b2[3] = {b2a, b2h, b2c};
  for (int p = 0; p < 3; p++)
    for (int m = 0; m < 6; m++){
      float s = 0.f;
      for (int l = 0; l < 6; l++) s += W2[p][m*6+l];
      outp[p*1536 + m*256 + g] = s * b1[p][g] + b2[p][m];
    }
}

__global__ void embed_enc_kernel(const int* __restrict__ input, const float* __restrict__ enc_emb,
                                 u16* __restrict__ x_emb){
  int i = blockIdx.x*256 + threadIdx.x;       // TIN*BB*EDIM threads
  int e = i & 255, b = (i >> 8) & 255, t = i >> 16;
  x_emb[i] = f2bf(enc_emb[(size_t)input[b*TIN + t]*EDIM + e]);
}

// pack fp32 weights -> bf16, row-permuted: dst row' = (d,ht,q,hh) -> g = q*256+ht*16+hh
__global__ void pack_w_kernel(const float* __restrict__ Wih, const float* __restrict__ Whh,
                              u16* __restrict__ dst, int K1, int K){
  int k = blockIdx.x*256 + threadIdx.x;
  int row = blockIdx.y;
  int d = row >> 10, rr = row & 1023;
  int g = ((rr>>4)&3)*256 + (rr>>6)*16 + (rr&15);
  float v;
  if (k < K1) v = Wih[((size_t)d*1024 + g)*K1 + k];
  else        v = Whh[((size_t)d*1024 + g)*256 + (k - K1)];
  dst[(size_t)row*K + k] = f2bf(v);
}

// bf16 copies of the three 256x256 W1s
__global__ void pack3_kernel(const float* __restrict__ a, const float* __restrict__ b, const float* __restrict__ c,
                             u16* __restrict__ oa, u16* __restrict__ ob, u16* __restrict__ oc){
  int i = blockIdx.x*256 + threadIdx.x;   // 65536
  oa[i] = f2bf(a[i]); ob[i] = f2bf(b[i]); oc[i] = f2bf(c[i]);
}

// composite decoder stage-0 weights + bias (Wc = Wih0 @ attn_W, b0' = b0 + Wih0@attn_b)
__global__ __launch_bounds__(256) void comp_w_kernel(
    const float* __restrict__ Wih0, const float* __restrict__ Whh0,
    const float* __restrict__ attn_W, const float* __restrict__ attn_b,
    const float* __restrict__ dec_b0, u16* __restrict__ wpk, float* __restrict__ b0p){
  __shared__ float sw[8][256];
  __shared__ float red[256];
  int tid = threadIdx.x;
  int rbase = blockIdx.x*8;
  int gs[8], ds[8];
  for (int r = 0; r < 8; r++){
    int row = rbase + r;
    int d = row >> 10, rr = row & 1023;
    int g = ((rr>>4)&3)*256 + (rr>>6)*16 + (rr&15);
    gs[r] = g; ds[r] = d;
    sw[r][tid] = Wih0[((size_t)d*1024 + g)*256 + tid];
  }
  __syncthreads();
  float a0[8], a1[8];
  #pragma unroll
  for (int r = 0; r < 8; r++){ a0[r]=0.f; a1[r]=0.f; }
  for (int e = 0; e < 256; e++){
    float w0 = attn_W[(size_t)e*512 + tid];
    float w1 = attn_W[(size_t)e*512 + 256 + tid];
    #pragma unroll
    for (int r = 0; r < 8; r++){ float s = sw[r][e]; a0[r] += s*w0; a1[r] += s*w1; }
  }
  for (int r = 0; r < 8; r++){
    int row = rbase + r;
    wpk[(size_t)row*768 + tid]       = f2bf(a0[r]);
    wpk[(size_t)row*768 + 256 + tid] = f2bf(a1[r]);
    wpk[(size_t)row*768 + 512 + tid] = f2bf(Whh0[((size_t)ds[r]*1024 + gs[r])*256 + tid]);
  }
  for (int r = 0; r < 8; r++){
    red[tid] = sw[r][tid]*attn_b[tid];
    __syncthreads();
    for (int s2 = 128; s2 > 0; s2 >>= 1){ if (tid < s2) red[tid] += red[tid+s2]; __syncthreads(); }
    if (tid == 0) b0p[ds[r]*1024 + gs[r]] = dec_b0[(size_t)ds[r]*1024 + gs[r]] + red[0];
    __syncthreads();
  }
}

// ==================== barrier: O(1) fan-in ====================
// Arrivals: per-block flag store (no RMW). Block 0's threads poll one flag each,
// then block 0 broadcasts via a single release word. flags strided 64 B.
__device__ __forceinline__ void gbar(int* __restrict__ flags, int* __restrict__ release, int& ep){
  __syncthreads();
  ep++;
  const int tid = threadIdx.x, bid = blockIdx.x;
  if (bid == 0){
    if (tid > 0){
      while (__hip_atomic_load(&flags[tid*16], __ATOMIC_RELAXED, __HIP_MEMORY_SCOPE_AGENT) < ep)
        __builtin_amdgcn_s_sleep(1);
    }
    __syncthreads();
    if (tid == 0){
      __threadfence();
      __hip_atomic_store(release, ep, __ATOMIC_RELEASE, __HIP_MEMORY_SCOPE_AGENT);
    }
    __syncthreads();
  } else {
    if (tid == 0){
      __threadfence();
      __hip_atomic_store(&flags[bid*16], ep, __ATOMIC_RELEASE, __HIP_MEMORY_SCOPE_AGENT);
      while (__hip_atomic_load(release, __ATOMIC_ACQUIRE, __HIP_MEMORY_SCOPE_AGENT) < ep)
        __builtin_amdgcn_s_sleep(8);
      __threadfence();
    }
    __syncthreads();
  }
}

// ==================== mega kernel units ====================

// fused LSTM stage unit: bid -> (m = bid>>5, d = (bid>>4)&1, ht = bid&15).
// Reads/writes only its own 32 rows of h slice idx -> in-place h is safe.
__device__ __forceinline__ void stage_unit(
    const u16* __restrict__ inp, int lda, int K1,
    const u16* __restrict__ Wpk, const float* __restrict__ bias_l,
    const u16* __restrict__ hR6, u16* __restrict__ hW6,
    float* __restrict__ cBuf, u16* __restrict__ inp_out, int l, char* smem){
  u16 (*As)[72] = (u16(*)[72])smem;                       // 32x72 = 4608 B
  u16 (*Ws)[72] = (u16(*)[72])(smem + 4608);              // 64x72 = 9216 B
  float (*Gt)[32][17] = (float(*)[32][17])(smem + 13824); // 8704 B
  int tid = threadIdx.x;
  int bid = blockIdx.x;
  int m_base = (bid >> 5)*32;
  int dht = bid & 31;
  int d = dht >> 4, ht = dht & 15;
  int idx = 2*l + d;
  int K = K1 + 256;
  const u16* Wblk = Wpk + (size_t)(dht*64)*K;
  const u16* A2 = hR6 + (size_t)idx*BH;
  int q = tid >> 6, lane = tid & 63;
  int ar = tid >> 3, kp = (tid & 7)*8;
  f32x4 acc0 = {0.f,0.f,0.f,0.f}, acc1 = {0.f,0.f,0.f,0.f};
  for (int c0 = 0; c0 < K; c0 += 64){
    int col = c0 + kp;
    const u16* ap = (col < K1) ? inp + (size_t)(m_base+ar)*lda + col
                               : A2  + (size_t)(m_base+ar)*HDIM + (col - K1);
    uint4 av  = *(const uint4*)ap;
    uint4 wv0 = *(const uint4*)(Wblk + (size_t)ar*K + col);
    uint4 wv1 = *(const uint4*)(Wblk + (size_t)(ar+32)*K + col);
    __syncthreads();
    *(uint4*)&As[ar][kp] = av;
    *(uint4*)&Ws[ar][kp] = wv0;
    *(uint4*)&Ws[ar+32][kp] = wv1;
    __syncthreads();
    #pragma unroll
    for (int kh = 0; kh < 2; kh++){
      int kb = kh*32 + (lane>>4)*8;
      bf16x8 a0v = ldbf8(&As[lane & 15][kb]);
      bf16x8 a1v = ldbf8(&As[16 + (lane & 15)][kb]);
      bf16x8 bq  = ldbf8(&Ws[q*16 + (lane & 15)][kb]);
      acc0 = mfma16(a0v, bq, acc0);
      acc1 = mfma16(a1v, bq, acc1);
    }
  }
  int hh = lane & 15, rq = lane >> 4;
  #pragma unroll
  for (int r = 0; r < 4; r++){
    Gt[q][rq*4 + r][hh]      = acc0[r];
    Gt[q][16 + rq*4 + r][hh] = acc1[r];
  }
  __syncthreads();
  const float* bias = bias_l + d*1024;
  #pragma unroll
  for (int it = 0; it < 2; it++){
    int id = tid + it*256;
    int bb = id >> 4, h2 = id & 15;
    int b = m_base + bb, h = ht*16 + h2;
    float iv = Gt[0][bb][h2] + bias[h];
    float fv = Gt[1][bb][h2] + bias[256 + h];
    float gv = Gt[2][bb][h2] + bias[512 + h];
    float ov = Gt[3][bb][h2] + bias[768 + h];
    size_t off = (size_t)idx*BH + (size_t)b*HDIM + h;
    float cold = cBuf[off];
    float cc = sigmf(fv)*cold + sigmf(iv)*tanhf(gv);
    float hv = sigmf(ov)*tanhf(cc);
    cBuf[off] = cc;
    u16 hb = f2bf(hv);
    hW6[off] = hb;
    if (inp_out) inp_out[(size_t)b*512 + d*HDIM + h] = hb;
  }
  __syncthreads();
}

// generic bf16 GEMM unit: C[32 x 64] = A[rows,256] @ W[n,256]^T + bias2d
// mode 0: bf16 row-major out; 1: fp32 row-major out; 2: eo2 scatter [b][m][t][n]
__device__ __forceinline__ void gemm_unit(
    const u16* __restrict__ A, const u16* __restrict__ W,
    const float* __restrict__ bias2, int r0, int n0, int mode,
    u16* __restrict__ outb, float* __restrict__ outf, char* smem){
  u16 (*As)[72] = (u16(*)[72])smem;
  u16 (*Ws)[72] = (u16(*)[72])(smem + 4608);
  int tid = threadIdx.x;
  int q = tid >> 6, lane = tid & 63;
  int ar = tid >> 3, kp = (tid & 7)*8;
  f32x4 acc0 = {0.f,0.f,0.f,0.f}, acc1 = {0.f,0.f,0.f,0.f};
  for (int c0 = 0; c0 < 256; c0 += 64){
    int col = c0 + kp;
    uint4 av  = *(const uint4*)(A + (size_t)(r0+ar)*256 + col);
    uint4 wv0 = *(const uint4*)(W + (size_t)(n0+ar)*256 + col);
    uint4 wv1 = *(const uint4*)(W + (size_t)(n0+ar+32)*256 + col);
    __syncthreads();
    *(uint4*)&As[ar][kp] = av;
    *(uint4*)&Ws[ar][kp] = wv0;
    *(uint4*)&Ws[ar+32][kp] = wv1;
    __syncthreads();
    #pragma unroll
    for (int kh = 0; kh < 2; kh++){
      int kb = kh*32 + (lane>>4)*8;
      bf16x8 a0v = ldbf8(&As[lane & 15][kb]);
      bf16x8 a1v = ldbf8(&As[16 + (lane & 15)][kb]);
      bf16x8 bq  = ldbf8(&Ws[q*16 + (lane & 15)][kb]);
      acc0 = mfma16(a0v, bq, acc0);
      acc1 = mfma16(a1v, bq, acc1);
    }
  }
  int hh = lane & 15, rq = lane >> 4;
  int n = n0 + q*16 + hh;
  #pragma unroll
  for (int r = 0; r < 4; r++){
    #pragma unroll
    for (int half = 0; half < 2; half++){
      int row = r0 + half*16 + rq*4 + r;
      float v = (half ? acc1[r] : acc0[r]) + bias2[((row>>8)%6)*256 + n];
      if (mode == 0)      outb[(size_t)row*256 + n] = f2bf(v);
      else if (mode == 1) outf[(size_t)row*256 + n] = v;
      else {
        int b = row & 255, mm = (row>>8)%6, t = row/1536;
        outb[(((size_t)(b*6 + mm)*32 + t)*256) + n] = f2bf(v);
      }
    }
  }
  __syncthreads();
}

__device__ __forceinline__ void attn_unit(const u16* __restrict__ hR, const u16* __restrict__ eo2,
                                          u16* __restrict__ embctx, const int* __restrict__ tf,
                                          float* __restrict__ attn_out, int step, int b){
  int hc = threadIdx.x;
  bool wa = (tf[0] == 0);
  float acc = 0.f;
  for (int d = 0; d < 6; d++){
    float hv = bf2f(hR[(size_t)d*BH + (size_t)b*256 + hc]);
    const u16* base = eo2 + ((size_t)(b*6 + d)*32)*256 + hc;
    float se = 0.f, ac = 0.f;
    #pragma unroll 8
    for (int t = 0; t < TIN; t++){
      float ev = bf2f(base[t*256]);
      float e = expf(hv*ev);
      se += e; ac += e*ev;
    }
    acc += ac/se;
    if (wa){
      float inv = 1.f/se;
      for (int t = 0; t < TIN; t++){
        float ev = bf2f(base[t*256]);
        atomicAdd(&attn_out[(((size_t)(step+1)*TIN + t)*DD + d)*BB + b], expf(hv*ev)*inv);
      }
    }
  }
  embctx[(size_t)b*512 + 256 + hc] = f2bf(acc*(1.0f/6.0f));
}

__device__ __forceinline__ void fc_unit(const u16* __restrict__ top, const float* __restrict__ fc_W,
                                        const float* __restrict__ fc_b, float* __restrict__ out,
                                        int slot, int b, char* smem){
  float* s  = (float*)smem;          // 512 f
  float* lg = (float*)(smem + 2048); // 72 f
  int tid = threadIdx.x;
  s[tid]       = bf2f(top[(size_t)b*512 + tid]);
  s[tid + 256] = bf2f(top[(size_t)b*512 + 256 + tid]);
  __syncthreads();
  if (tid < VDEC){
    float a = fc_b[tid];
    const float4* wr = (const float4*)(fc_W + (size_t)tid*512);
    for (int k = 0; k < 128; k++){
      float4 w = wr[k];
      a += s[4*k]*w.x + s[4*k+1]*w.y + s[4*k+2]*w.z + s[4*k+3]*w.w;
    }
    out[((size_t)slot*256 + b)*VDEC + tid] = a;
    lg[tid] = a;
  }
  __syncthreads();
}

__device__ __forceinline__ void emb_unit(int i, const int* __restrict__ tf, const int* __restrict__ target,
                                         const float* __restrict__ lg, const float* __restrict__ dec_emb,
                                         u16* __restrict__ embctx, int b, char* smem){
  int* tokp = (int*)(smem + 2368);
  int tid = threadIdx.x;
  if (tid == 0){
    int tok;
    if (tf[0]) tok = target[b*TOUT + i];
    else if (i == 0) tok = 1;
    else {
      tok = 0; float bv = lg[0];
      for (int v = 1; v < VDEC; v++){ float x = lg[v]; if (x > bv){ bv = x; tok = v; } }
    }
    *tokp = tok;
  }
  __syncthreads();
  int tok = *tokp;
  embctx[(size_t)b*512 + tid] = f2bf(dec_emb[(size_t)tok*EDIM + tid]);
  __syncthreads();
}

struct MegaArgs {
  const int *target, *tf;
  const float *enc_b, *dec_b, *fc_W, *fc_b, *dec_emb;
  const float *lin_h_W2, *lin_c_W2, *lin_a_W2;
  const u16 *x_emb, *wp_e0, *wp_e1, *wp_e2, *wp_dc0, *wp_d1, *wp_d2;
  const float *dc_b0p;
  const u16 *w1h, *w1c, *w1a;
  const float *bias2d;
  u16 *h_all_bf, *hzero;
  float *enc_c;
  u16 *l0out0, *l0out1, *l1out0, *l1out1;
  u16 *tmp6hc;
  u16 *eo2, *dec_h;
  float *dec_c;
  u16 *bufA, *bufB, *bufC, *embctx;
  float *out, *attn_out;
  int *flags, *release;
};

__global__ __launch_bounds__(256, 1) void mega_kernel(MegaArgs a){
  __shared__ __align__(16) char smem[23040];
  int ep = 0;
  int bid = blockIdx.x, tid = threadIdx.x;
  u16* l0out[2] = { a.l0out0, a.l0out1 };
  u16* l1out[2] = { a.l1out0, a.l1out1 };
  // -------- encoder: wavefront over (t, l), 34 phases --------
  for (int p = 0; p < TIN + 2; p++){
    for (int l = 0; l < 3; l++){
      int t = p - l;
      if (t < 0 || t >= TIN) continue;
      const u16* hR6 = (t == 0) ? a.hzero : a.h_all_bf + (size_t)(t-1)*6*BH;
      u16* hW6 = a.h_all_bf + (size_t)t*6*BH;
      if (l == 0)
        stage_unit(a.x_emb + (size_t)t*BB*256, 256, 256, a.wp_e0, a.enc_b,
                   hR6, hW6, a.enc_c, l0out[t&1], 0, smem);
      else if (l == 1)
        stage_unit(l0out[t&1], 512, 512, a.wp_e1, a.enc_b + 2048,
                   hR6, hW6, a.enc_c, l1out[t&1], 1, smem);
      else
        stage_unit(l1out[t&1], 512, 512, a.wp_e2, a.enc_b + 4096,
                   hR6, hW6, a.enc_c, nullptr, 2, smem);
    }
    gbar(a.flags, a.release, ep);
  }
  // -------- B1: W2-mixes (thread owns (b=bid, h=tid)) --------
  {
    float* sW2 = (float*)smem;    // 108 f
    if (tid < 108){
      int p = tid/36, j = tid%36;
      const float* src = (p==0)? a.lin_h_W2 : (p==1 ? a.lin_c_W2 : a.lin_a_W2);
      sW2[tid] = src[j];
    }
    __syncthreads();
    int b = bid, h = tid;
    float v[6];
    #pragma unroll
    for (int l2 = 0; l2 < 6; l2++) v[l2] = bf2f(a.h_all_bf[((size_t)(31*6 + l2)*BB + b)*256 + h]);
    #pragma unroll
    for (int m = 0; m < 6; m++){
      float o = 0.f;
      #pragma unroll
      for (int l2 = 0; l2 < 6; l2++) o += sW2[m*6+l2]*v[l2];
      a.tmp6hc[((size_t)(m*256 + b))*256 + h] = f2bf(o);
    }
    #pragma unroll
    for (int l2 = 0; l2 < 6; l2++) v[l2] = a.enc_c[(size_t)l2*BH + (size_t)b*256 + h];
    #pragma unroll
    for (int m = 0; m < 6; m++){
      float o = 0.f;
      #pragma unroll
      for (int l2 = 0; l2 < 6; l2++) o += sW2[36 + m*6+l2]*v[l2];
      a.tmp6hc[((size_t)(1536 + m*256 + b))*256 + h] = f2bf(o);
    }
    for (int t = 0; t < TIN; t++){
      #pragma unroll
      for (int l2 = 0; l2 < 6; l2++) v[l2] = bf2f(a.h_all_bf[((size_t)(t*6 + l2)*BB + b)*256 + h]);
      #pragma unroll
      for (int m = 0; m < 6; m++){
        float o = 0.f;
        #pragma unroll
        for (int l2 = 0; l2 < 6; l2++) o += sW2[72 + m*6+l2]*v[l2];
        a.h_all_bf[((size_t)(t*6 + m)*BB + b)*256 + h] = f2bf(o);
      }
    }
  }
  gbar(a.flags, a.release, ep);
  // -------- B2: bridge GEMMs + attention projection --------
  for (int u = bid; u < 6528; u += NB){
    if (u < 192){
      int r0 = (u>>2)*32, n0 = (u&3)*64;
      gemm_unit(a.tmp6hc, a.w1h, a.bias2d + 1536, r0, n0, 0, a.dec_h, nullptr, smem);
    } else if (u < 384){
      int v2 = u - 192;
      int r0 = (v2>>2)*32, n0 = (v2&3)*64;
      gemm_unit(a.tmp6hc + (size_t)1536*256, a.w1c, a.bias2d + 3072, r0, n0, 1, nullptr, a.dec_c, smem);
    } else {
      int at = u - 384;
      int r0 = (at>>2)*32, n0 = (at&3)*64;
      gemm_unit(a.h_all_bf, a.w1a, a.bias2d, r0, n0, 2, a.eo2, nullptr, smem);
    }
  }
  gbar(a.flags, a.release, ep);
  // -------- decoder: 28 steps x 4 phases (chain is irreducible) --------
  for (int i = 0; i < TOUT-1; i++){
    attn_unit(a.dec_h, a.eo2, a.embctx, a.tf, a.attn_out, i, bid);
    if (i > 0) fc_unit(a.bufC, a.fc_W, a.fc_b, a.out, i, bid, smem);
    emb_unit(i, a.tf, a.target, (const float*)(smem + 2048), a.dec_emb, a.embctx, bid, smem);
    gbar(a.flags, a.release, ep);
    stage_unit(a.embctx, 512, 512, a.wp_dc0, a.dc_b0p,       a.dec_h, a.dec_h, a.dec_c, a.bufA, 0, smem);
    gbar(a.flags, a.release, ep);
    stage_unit(a.bufA, 512, 512, a.wp_d1, a.dec_b + 2048, a.dec_h, a.dec_h, a.dec_c, a.bufB, 1, smem);
    gbar(a.flags, a.release, ep);
    stage_unit(a.bufB, 512, 512, a.wp_d2, a.dec_b + 4096, a.dec_h, a.dec_h, a.dec_c, a.bufC, 2, smem);
    gbar(a.flags, a.release, ep);
  }
  fc_unit(a.bufC, a.fc_W, a.fc_b, a.out, TOUT-1, bid, smem);
}

// =====================================================================

extern "C" void kernel_launch(void* const* d_in, const int* in_sizes, int n_in,
                              void* d_out, int out_size, void* d_ws, size_t ws_size,
                              hipStream_t stream){
  (void)in_sizes; (void)n_in; (void)out_size; (void)ws_size;
  const int*   input    = (const int*)d_in[0];
  const int*   target   = (const int*)d_in[1];
  const int*   tf       = (const int*)d_in[2];
  const float* enc_emb  = (const float*)d_in[3];
  const float* dec_emb  = (const float*)d_in[4];
  const float* enc_Wih0 = (const float*)d_in[5];
  const float* enc_Wih1 = (const float*)d_in[6];
  const float* enc_Whh  = (const float*)d_in[7];
  const float* enc_b    = (const float*)d_in[8];
  const float* dec_Wih0 = (const float*)d_in[9];
  const float* dec_Wih1 = (const float*)d_in[10];
  const float* dec_Whh  = (const float*)d_in[11];
  const float* dec_b    = (const float*)d_in[12];
  const float* lin_h_W1 = (const float*)d_in[13];
  const float* lin_h_b1 = (const float*)d_in[14];
  const float* lin_h_W2 = (const float*)d_in[15];
  const float* lin_h_b2 = (const float*)d_in[16];
  const float* lin_c_W1 = (const float*)d_in[17];
  const float* lin_c_b1 = (const float*)d_in[18];
  const float* lin_c_W2 = (const float*)d_in[19];
  const float* lin_c_b2 = (const float*)d_in[20];
  const float* lin_a_W1 = (const float*)d_in[21];
  const float* lin_a_b1 = (const float*)d_in[22];
  const float* lin_a_W2 = (const float*)d_in[23];
  const float* lin_a_b2 = (const float*)d_in[24];
  const float* attn_W   = (const float*)d_in[25];
  const float* attn_b   = (const float*)d_in[26];
  const float* fc_W     = (const float*)d_in[27];
  const float* fc_b     = (const float*)d_in[28];
  float* out = (float*)d_out;

  char* base = (char*)d_ws;
  size_t off = 0;
  auto alloc = [&](size_t bytes)->char*{
    char* p = base + off; off += (bytes + 255) & ~(size_t)255; return p;
  };
  // ---- zero block: [flags | release | hzero(bf16) | enc_c(f32)] contiguous ----
  int*   flags   = (int*)alloc(sizeof(int)*256*16);        // 16 KB, 64B stride
  int*   release = (int*)alloc(256);
  u16*   hzero   = (u16*)alloc(sizeof(u16)*(size_t)DD*BH);
  float* enc_c   = (float*)alloc(sizeof(float)*(size_t)DD*BH);
  size_t zero_bytes = (char*)(enc_c + (size_t)DD*BH) - (char*)flags;
  size_t zero_u32 = zero_bytes/4;

  u16*   dec_h  = (u16*)alloc(sizeof(u16)*(size_t)DD*BH);
  float* dec_c  = (float*)alloc(sizeof(float)*(size_t)DD*BH);
  u16*   tmp6hc = (u16*)alloc(sizeof(u16)*(size_t)2*1536*256);
  u16*   h_all  = (u16*)alloc(sizeof(u16)*(size_t)TIN*DD*BH);
  u16*   eo2    = (u16*)alloc(sizeof(u16)*(size_t)TIN*DD*BH);
  u16*   x_emb  = (u16*)alloc(sizeof(u16)*(size_t)TIN*BB*EDIM);
  u16*   l0out0 = (u16*)alloc(sizeof(u16)*(size_t)BB*512);
  u16*   l0out1 = (u16*)alloc(sizeof(u16)*(size_t)BB*512);
  u16*   l1out0 = (u16*)alloc(sizeof(u16)*(size_t)BB*512);
  u16*   l1out1 = (u16*)alloc(sizeof(u16)*(size_t)BB*512);
  u16*   bufA   = (u16*)alloc(sizeof(u16)*(size_t)BB*512);
  u16*   bufB   = (u16*)alloc(sizeof(u16)*(size_t)BB*512);
  u16*   bufC   = (u16*)alloc(sizeof(u16)*(size_t)BB*512);
  u16*   embctx = (u16*)alloc(sizeof(u16)*(size_t)BB*512);
  float* bias2d = (float*)alloc(sizeof(float)*3*6*256);
  float* dc_b0p = (float*)alloc(sizeof(float)*2048);
  u16*   w1h    = (u16*)alloc(sizeof(u16)*65536);
  u16*   w1c    = (u16*)alloc(sizeof(u16)*65536);
  u16*   w1a    = (u16*)alloc(sizeof(u16)*65536);
  u16*   wp_e0  = (u16*)alloc(sizeof(u16)*(size_t)2048*512);
  u16*   wp_e1  = (u16*)alloc(sizeof(u16)*(size_t)2048*768);
  u16*   wp_e2  = (u16*)alloc(sizeof(u16)*(size_t)2048*768);
  u16*   wp_dc0 = (u16*)alloc(sizeof(u16)*(size_t)2048*768);
  u16*   wp_d1  = (u16*)alloc(sizeof(u16)*(size_t)2048*768);
  u16*   wp_d2  = (u16*)alloc(sizeof(u16)*(size_t)2048*768);

  const int outn = TOUT*BB*VDEC + TOUT*TIN*DD*BB;
  init_out_kernel<<<(outn+255)/256, 256, 0, stream>>>(out, outn);
  fill_zero_u32<<<((int)zero_u32+255)/256, 256, 0, stream>>>((u32*)flags, (int)zero_u32);
  bias2d_kernel<<<1, 256, 0, stream>>>(lin_a_W2, lin_a_b1, lin_a_b2,
                                       lin_h_W2, lin_h_b1, lin_h_b2,
                                       lin_c_W2, lin_c_b1, lin_c_b2, bias2d);
  embed_enc_kernel<<<(TIN*BB*EDIM)/256, 256, 0, stream>>>(input, enc_emb, x_emb);
  pack_w_kernel<<<dim3(2,2048), 256, 0, stream>>>(enc_Wih0, enc_Whh,                       wp_e0, 256, 512);
  pack_w_kernel<<<dim3(3,2048), 256, 0, stream>>>(enc_Wih1, enc_Whh + 2*1024*256,          wp_e1, 512, 768);
  pack_w_kernel<<<dim3(3,2048), 256, 0, stream>>>(enc_Wih1 + (size_t)2*1024*512, enc_Whh + 4*1024*256, wp_e2, 512, 768);
  pack_w_kernel<<<dim3(3,2048), 256, 0, stream>>>(dec_Wih1, dec_Whh + 2*1024*256,          wp_d1, 512, 768);
  pack_w_kernel<<<dim3(3,2048), 256, 0, stream>>>(dec_Wih1 + (size_t)2*1024*512, dec_Whh + 4*1024*256, wp_d2, 512, 768);
  pack3_kernel<<<256, 256, 0, stream>>>(lin_h_W1, lin_c_W1, lin_a_W1, w1h, w1c, w1a);
  comp_w_kernel<<<256, 256, 0, stream>>>(dec_Wih0, dec_Whh, attn_W, attn_b, dec_b, wp_dc0, dc_b0p);

  MegaArgs a;
  a.target = target; a.tf = tf;
  a.enc_b = enc_b; a.dec_b = dec_b; a.fc_W = fc_W; a.fc_b = fc_b; a.dec_emb = dec_emb;
  a.lin_h_W2 = lin_h_W2; a.lin_c_W2 = lin_c_W2; a.lin_a_W2 = lin_a_W2;
  a.x_emb = x_emb; a.wp_e0 = wp_e0; a.wp_e1 = wp_e1; a.wp_e2 = wp_e2;
  a.wp_dc0 = wp_dc0; a.wp_d1 = wp_d1; a.wp_d2 = wp_d2;
  a.dc_b0p = dc_b0p; a.w1h = w1h; a.w1c = w1c; a.w1a = w1a; a.bias2d = bias2d;
  a.h_all_bf = h_all; a.hzero = hzero; a.enc_c = enc_c;
  a.l0out0 = l0out0; a.l0out1 = l0out1; a.l1out0 = l1out0; a.l1out1 = l1out1;
  a.tmp6hc = tmp6hc; a.eo2 = eo2; a.dec_h = dec_h; a.dec_c = dec_c;
  a.bufA = bufA; a.bufB = bufB; a.bufC = bufC; a.embctx = embctx;
  a.out = out; a.attn_out = out + (size_t)TOUT*BB*VDEC;
  a.flags = flags; a.release = release;
  mega_kernel<<<NB, 256, 0, stream>>>(a);
}

// Round 5
// 4177.756 us; speedup vs baseline: 1.7595x; 1.3741x over previous
//
#include <hip/hip_runtime.h>
#include <math.h>

#define BB 256
#define TIN 32
#define TOUT 29
#define VDEC 72
#define EDIM 256
#define HDIM 256
#define DD 6
#define BH (BB*HDIM)
#define NB 256

typedef unsigned short u16;
typedef unsigned int u32;
typedef unsigned long long u64;
typedef __bf16 bf16x8 __attribute__((ext_vector_type(8)));
typedef float f32x4 __attribute__((ext_vector_type(4)));
typedef u16 u16x8 __attribute__((ext_vector_type(8)));

__device__ __forceinline__ float sigmf(float x){ return 1.0f/(1.0f+expf(-x)); }
__device__ __forceinline__ u16 f2bf(float f){
  u32 u = __builtin_bit_cast(u32, f);
  u32 r = (u + 0x7fffu + ((u>>16)&1u)) >> 16;
  return (u16)r;
}
__device__ __forceinline__ float bf2f(u16 s){
  u32 u = ((u32)s)<<16; return __builtin_bit_cast(float, u);
}
__device__ __forceinline__ bf16x8 ldbf8(const u16* p){
  u16x8 t = *(const u16x8*)p; return __builtin_bit_cast(bf16x8, t);
}
__device__ __forceinline__ f32x4 mfma16(bf16x8 a, bf16x8 b, f32x4 c){
  return __builtin_amdgcn_mfma_f32_16x16x32_bf16(a, b, c, 0, 0, 0);
}
// L3-coherent (sc1) accessors: relaxed agent-scope atomics bypass per-XCD L2,
// no cache-maintenance instructions emitted.
__device__ __forceinline__ u32 ld_sc1(const u32* p){
  return __hip_atomic_load(p, __ATOMIC_RELAXED, __HIP_MEMORY_SCOPE_AGENT);
}
__device__ __forceinline__ u64 ld_sc1_64(const void* p){
  return __hip_atomic_load((const u64*)p, __ATOMIC_RELAXED, __HIP_MEMORY_SCOPE_AGENT);
}
__device__ __forceinline__ void st_sc1(u32* p, u32 v){
  __hip_atomic_store(p, v, __ATOMIC_RELAXED, __HIP_MEMORY_SCOPE_AGENT);
}
__device__ __forceinline__ float ldf_sc1(const float* p){
  return __builtin_bit_cast(float, ld_sc1((const u32*)p));
}
__device__ __forceinline__ void stf_sc1(float* p, float v){
  st_sc1((u32*)p, __builtin_bit_cast(u32, v));
}
__device__ __forceinline__ u16 half_sc1(const u16* p, int odd_sel){
  u32 v = ld_sc1((const u32*)(p - odd_sel));
  return odd_sel ? (u16)(v>>16) : (u16)v;
}

// ==================== merged setup kernel ====================
struct SetupArgs {
  const float *enc_Wih0,*enc_Wih1,*enc_Whh,*enc_b;
  const float *dec_Wih0,*dec_Wih1,*dec_Whh,*dec_b;
  const float *lin_h_W1,*lin_c_W1,*lin_a_W1, *dec_emb, *enc_emb;
  const float *attn_W,*attn_b;
  const float *aW2,*ab1,*ab2,*hW2,*hb1,*hb2,*cW2,*cb1,*cb2;
  const int* input;
  u16 *wp_e0,*wp_e1,*wp_e2,*wp_d1,*wp_d2,*wp_dc0;
  u16 *w1h,*w1c,*w1a,*demb16,*x_emb;
  float *bias2d,*dc_b0p;
  u32* zero_ptr; int zero_n;
  float* out; int out_n;
};

__device__ void pack_seg(int j, int nch, const float* Wih, const float* Whh,
                         u16* dst, int K1, int K){
  int row = j / nch, chunk = j % nch;
  int k = chunk*256 + threadIdx.x;
  int d = row >> 10, rr = row & 1023;
  int g = ((rr>>4)&3)*256 + (rr>>6)*16 + (rr&15);
  float v;
  if (k < K1) v = Wih[((size_t)d*1024 + g)*K1 + k];
  else        v = Whh[((size_t)d*1024 + g)*256 + (k - K1)];
  dst[(size_t)row*K + k] = f2bf(v);
}

__global__ __launch_bounds__(256) void setup_kernel(SetupArgs s){
  __shared__ float sw[8][256];
  __shared__ float red[256];
  int j = blockIdx.x, tid = threadIdx.x;
  if (j < 4096){ pack_seg(j, 2, s.enc_Wih0, s.enc_Whh, s.wp_e0, 256, 512); return; }
  j -= 4096;
  if (j < 6144){ pack_seg(j, 3, s.enc_Wih1, s.enc_Whh + 2*1024*256, s.wp_e1, 512, 768); return; }
  j -= 6144;
  if (j < 6144){ pack_seg(j, 3, s.enc_Wih1 + (size_t)2*1024*512, s.enc_Whh + 4*1024*256, s.wp_e2, 512, 768); return; }
  j -= 6144;
  if (j < 6144){ pack_seg(j, 3, s.dec_Wih1, s.dec_Whh + 2*1024*256, s.wp_d1, 512, 768); return; }
  j -= 6144;
  if (j < 6144){ pack_seg(j, 3, s.dec_Wih1 + (size_t)2*1024*512, s.dec_Whh + 4*1024*256, s.wp_d2, 512, 768); return; }
  j -= 6144;
  if (j < 256){ int i=j*256+tid; s.w1h[i]=f2bf(s.lin_h_W1[i]); s.w1c[i]=f2bf(s.lin_c_W1[i]); s.w1a[i]=f2bf(s.lin_a_W1[i]); return; }
  j -= 256;
  if (j < 72){ int i=j*256+tid; s.demb16[i]=f2bf(s.dec_emb[i]); return; }
  j -= 72;
  if (j < 256){
    // composite decoder stage-0 weights + bias
    int rbase = j*8;
    int gs[8], ds[8];
    for (int r=0;r<8;r++){
      int row=rbase+r; int d=row>>10, rr=row&1023;
      int g=((rr>>4)&3)*256+(rr>>6)*16+(rr&15);
      gs[r]=g; ds[r]=d;
      sw[r][tid]=s.dec_Wih0[((size_t)d*1024+g)*256+tid];
    }
    __syncthreads();
    float a0[8],a1[8];
    #pragma unroll
    for (int r=0;r<8;r++){a0[r]=0.f;a1[r]=0.f;}
    for (int e=0;e<256;e++){
      float w0=s.attn_W[(size_t)e*512+tid];
      float w1=s.attn_W[(size_t)e*512+256+tid];
      #pragma unroll
      for (int r=0;r<8;r++){float sv=sw[r][e];a0[r]+=sv*w0;a1[r]+=sv*w1;}
    }
    for (int r=0;r<8;r++){
      int row=rbase+r;
      s.wp_dc0[(size_t)row*768+tid]      =f2bf(a0[r]);
      s.wp_dc0[(size_t)row*768+256+tid]  =f2bf(a1[r]);
      s.wp_dc0[(size_t)row*768+512+tid]  =f2bf(s.dec_Whh[((size_t)ds[r]*1024+gs[r])*256+tid]);
    }
    for (int r=0;r<8;r++){
      red[tid]=sw[r][tid]*s.attn_b[tid];
      __syncthreads();
      for (int s2=128;s2>0;s2>>=1){ if (tid<s2) red[tid]+=red[tid+s2]; __syncthreads(); }
      if (tid==0) s.dc_b0p[ds[r]*1024+gs[r]] = s.dec_b[(size_t)ds[r]*1024+gs[r]] + red[0];
      __syncthreads();
    }
    return;
  }
  j -= 256;
  if (j < 1){
    int g = tid;
    const float* W2[3]={s.aW2,s.hW2,s.cW2};
    const float* b1[3]={s.ab1,s.hb1,s.cb1};
    const float* b2[3]={s.ab2,s.hb2,s.cb2};
    for (int p=0;p<3;p++)
      for (int m=0;m<6;m++){
        float sm=0.f;
        for (int l=0;l<6;l++) sm+=W2[p][m*6+l];
        s.bias2d[p*1536+m*256+g]=sm*b1[p][g]+b2[p][m];
      }
    return;
  }
  j -= 1;
  if (j < 8192){
    int i=j*256+tid;
    int e=i&255,b=(i>>8)&255,t=i>>16;
    s.x_emb[i]=f2bf(s.enc_emb[(size_t)s.input[b*TIN+t]*EDIM+e]);
    return;
  }
  j -= 8192;
  { // zero region then init_out
    int zb = (s.zero_n + 255)/256;
    if (j < zb){ int i=j*256+tid; if (i<s.zero_n) s.zero_ptr[i]=0u; return; }
    j -= zb;
    int i=j*256+tid;
    if (i < s.out_n){
      float v=0.f;
      if (i < BB*VDEC && (i%VDEC)==1) v=1.0f;
      s.out[i]=v;
    }
  }
}

// ==================== barrier: fence-free, O(1) fan-in ====================
__device__ __forceinline__ void gbar(int* __restrict__ flags, int* __restrict__ release, int& ep){
  asm volatile("" ::: "memory");
  __builtin_amdgcn_s_waitcnt(0);     // my wave's sc1 stores at coherence point
  __syncthreads();                   // all waves of block drained
  ep++;
  int tid=threadIdx.x, bid=blockIdx.x;
  if (bid == 0){
    if (tid > 0){
      while ((int)ld_sc1((u32*)&flags[tid*16]) < ep) __builtin_amdgcn_s_sleep(1);
    }
    __syncthreads();
    if (tid == 0) st_sc1((u32*)release, (u32)ep);
    __syncthreads();
  } else {
    if (tid == 0){
      st_sc1((u32*)&flags[bid*16], (u32)ep);
      while ((int)ld_sc1((u32*)release) < ep) __builtin_amdgcn_s_sleep(2);
    }
    __syncthreads();
  }
  asm volatile("" ::: "memory");
}

// ==================== stage unit ====================
// MODE 0: A1 normal (x_emb).  MODE 1: A1 sc1 (bufs/embctx).  MODE 2: dec s0
// (emb-gather from demb16 + pctx mean + h).  K total (incl. 256 h-cols).
template<int K, int MODE>
__device__ void stage_unit(const u16* __restrict__ A1,
    const u16* __restrict__ Wpk, const float* __restrict__ bias_l,
    const u16* __restrict__ hR6, u16* __restrict__ hW6, float* __restrict__ c6,
    u16* __restrict__ inp_out, int l,
    const int* __restrict__ target, int step, const float* __restrict__ pctx_in,
    float* __restrict__ pctx_out, const u16* __restrict__ eo2, char* smem)
{
  constexpr int K1 = K - 256;
  constexpr int UPT = K/16;          // u32 per thread (32 or 48)
  int tid=threadIdx.x, bid=blockIdx.x;
  int m_base=(bid>>5)*32, dht=bid&31, d=dht>>4, ht=dht&15, idx=2*l+d;
  u16 (*As)[776] = (u16(*)[776])smem;
  float (*Gt)[32][17] = (float(*)[32][17])(smem + 49664);
  __syncthreads();                   // guard smem reuse across units
  float cpre[2];
  #pragma unroll
  for (int it=0; it<2; it++){
    int id=tid+it*256;
    size_t off=(size_t)idx*BH+(size_t)(m_base+(id>>4))*HDIM + ht*16+(id&15);
    cpre[it]=ldf_sc1(c6+off);
  }
  int row = tid>>3;
  int cu0 = (tid&7)*UPT;
  const u16* hrow = hR6 + (size_t)idx*BH + (size_t)(m_base+row)*HDIM;
  u32 vals[UPT];
  if (MODE==2){
    int tok = target[(m_base+row)*TOUT + step];
    const u16* erow = A1 + (size_t)tok*256;
    const float* prow = pctx_in + (size_t)(m_base+row)*256;
    #pragma unroll
    for (int i=0;i<UPT;i++){
      int col=(cu0+i)*2;
      u32 v;
      if (col<256) v = *(const u32*)(erow+col);
      else if (col<512){
        u64 pv = ld_sc1_64(prow+(col-256));
        float f0=__builtin_bit_cast(float,(u32)pv);
        float f1=__builtin_bit_cast(float,(u32)(pv>>32));
        v = (u32)f2bf(f0*(1.f/6.f)) | ((u32)f2bf(f1*(1.f/6.f))<<16);
      } else v = ld_sc1((const u32*)(hrow+(col-512)));
      vals[i]=v;
    }
  } else {
    const u16* arow = A1 + (size_t)(m_base+row)*K1;
    #pragma unroll
    for (int i=0;i<UPT;i++){
      int col=(cu0+i)*2;
      u32 v;
      if (col<K1) v = (MODE==1) ? ld_sc1((const u32*)(arow+col)) : *(const u32*)(arow+col);
      else v = ld_sc1((const u32*)(hrow+(col-K1)));
      vals[i]=v;
    }
  }
  u32* lrow = (u32*)&As[row][0];
  #pragma unroll
  for (int i=0;i<UPT;i++) lrow[cu0+i]=vals[i];
  __syncthreads();
  int q=tid>>6, lane=tid&63;
  const u16* wrow = Wpk + (size_t)(dht*64 + q*16 + (lane&15))*K;
  f32x4 acc0={0.f,0.f,0.f,0.f}, acc1={0.f,0.f,0.f,0.f};
  #pragma unroll
  for (int c0=0;c0<K;c0+=32){
    int kb=c0+(lane>>4)*8;
    bf16x8 a0=ldbf8(&As[lane&15][kb]);
    bf16x8 a1=ldbf8(&As[16+(lane&15)][kb]);
    bf16x8 bq=ldbf8(wrow+kb);         // direct global W gather (L2-cached)
    acc0=mfma16(a0,bq,acc0); acc1=mfma16(a1,bq,acc1);
  }
  int hh=lane&15, rq=lane>>4;
  #pragma unroll
  for (int r=0;r<4;r++){ Gt[q][rq*4+r][hh]=acc0[r]; Gt[q][16+rq*4+r][hh]=acc1[r]; }
  __syncthreads();
  const float* bias = bias_l + d*1024;
  #pragma unroll
  for (int it=0; it<2; it++){
    int id=tid+it*256, bb=id>>4, h2=id&15;
    int b=m_base+bb, h=ht*16+h2;
    float iv=Gt[0][bb][h2]+bias[h];
    float fv=Gt[1][bb][h2]+bias[256+h];
    float gv=Gt[2][bb][h2]+bias[512+h];
    float ov=Gt[3][bb][h2]+bias[768+h];
    size_t off=(size_t)idx*BH+(size_t)b*HDIM+h;
    float cc=sigmf(fv)*cpre[it]+sigmf(iv)*tanhf(gv);
    float hv=sigmf(ov)*tanhf(cc);
    stf_sc1(c6+off, cc);
    u16 hb=f2bf(hv);
    u32 other=(u32)__shfl_xor((int)(u32)hb,1,64);
    if (!(h2&1)){
      u32 pair=((u32)hb)|(other<<16);
      st_sc1((u32*)(hW6+off), pair);
      if (inp_out) st_sc1((u32*)(inp_out+(size_t)b*512+d*256+h), pair);
    }
    if (pctx_out){
      const u16* eb = eo2 + ((size_t)(b*6+idx)*32)*256 + h;  // normal (L2)
      float se=0.f, ac=0.f;
      #pragma unroll 8
      for (int t=0;t<TIN;t++){
        float ev=bf2f(eb[t*256]); float e=expf(hv*ev); se+=e; ac+=e*ev;
      }
      atomicAdd(&pctx_out[(size_t)b*256+h], ac/se);
    }
  }
}

// ==================== B2 GEMM unit (K=256) ====================
// mode 0: bf16 row-major (dec_h0); 1: f32 row-major (dec_c); 2: eo2 scatter
__device__ void gemm_unit(const u16* __restrict__ A, const u16* __restrict__ W,
    const float* __restrict__ bias2, int r0, int n0, int mode,
    u16* __restrict__ outb, float* __restrict__ outf, char* smem)
{
  u16 (*As)[264] = (u16(*)[264])smem;
  int tid=threadIdx.x;
  __syncthreads();
  int row=tid>>3, cu0=(tid&7)*16;
  const u32* arow=(const u32*)(A+(size_t)(r0+row)*256);
  u32 vals[16];
  #pragma unroll
  for (int i=0;i<16;i++) vals[i]=ld_sc1(arow+cu0+i);
  u32* lrow=(u32*)&As[row][0];
  #pragma unroll
  for (int i=0;i<16;i++) lrow[cu0+i]=vals[i];
  __syncthreads();
  int q=tid>>6, lane=tid&63;
  const u16* wrow = W + (size_t)(n0+q*16+(lane&15))*256;
  f32x4 acc0={0.f,0.f,0.f,0.f}, acc1={0.f,0.f,0.f,0.f};
  #pragma unroll
  for (int c0=0;c0<256;c0+=32){
    int kb=c0+(lane>>4)*8;
    bf16x8 a0=ldbf8(&As[lane&15][kb]);
    bf16x8 a1=ldbf8(&As[16+(lane&15)][kb]);
    bf16x8 bq=ldbf8(wrow+kb);
    acc0=mfma16(a0,bq,acc0); acc1=mfma16(a1,bq,acc1);
  }
  int hh=lane&15, rq=lane>>4;
  int n=n0+q*16+hh;
  #pragma unroll
  for (int half=0; half<2; half++){
    #pragma unroll
    for (int r=0;r<4;r++){
      int rowo=r0+half*16+rq*4+r;
      float v=(half?acc1[r]:acc0[r]) + bias2[((rowo>>8)%6)*256+n];
      if (mode==1){ stf_sc1(outf+(size_t)rowo*256+n, v); }
      else {
        u16 b16=f2bf(v);
        u32 other=(u32)__shfl_xor((int)(u32)b16,1,64);
        if (!(hh&1)){
          u32 pair=((u32)b16)|(other<<16);
          size_t addr;
          if (mode==0) addr=(size_t)rowo*256+n;
          else { int b=rowo&255, mm=(rowo>>8)%6, t=rowo/1536; addr=(((size_t)(b*6+mm)*32+t)*256)+n; }
          st_sc1((u32*)(outb+addr), pair);
        }
      }
    }
  }
}

// ==================== fc fold (logits for one b per block) ====================
__device__ void fc_fold(const u16* __restrict__ bufC, const float* __restrict__ fc_W,
                        const float* __restrict__ fc_b, float* __restrict__ out,
                        int slot, float* lg_opt, char* smem)
{
  float* s  = (float*)smem;            // 512 f
  float* red= (float*)(smem+2048);     // 144 f
  int tid=threadIdx.x, b=blockIdx.x;
  u32 v=ld_sc1((const u32*)bufC + (size_t)b*256 + tid);
  s[2*tid]=bf2f((u16)v); s[2*tid+1]=bf2f((u16)(v>>16));
  __syncthreads();
  if (tid<144){
    int vv = (tid<72)? tid : tid-72;
    int hf = (tid<72)? 0 : 1;
    const float* wr = fc_W + (size_t)vv*512 + hf*256;
    const float* sp = s + hf*256;
    float a0=0.f,a1=0.f,a2=0.f,a3=0.f;
    #pragma unroll 16
    for (int k=0;k<256;k+=4){
      a0+=sp[k]*wr[k]; a1+=sp[k+1]*wr[k+1]; a2+=sp[k+2]*wr[k+2]; a3+=sp[k+3]*wr[k+3];
    }
    red[tid]=a0+a1+a2+a3;
  }
  __syncthreads();
  if (tid<72){
    float a=red[tid]+red[tid+72]+fc_b[tid];
    out[((size_t)slot*256+b)*VDEC+tid]=a;
    if (lg_opt) lg_opt[tid]=a;
  }
  __syncthreads();
}

struct MegaArgs {
  const int *target, *tf;
  const float *enc_b, *dec_b, *fc_W, *fc_b;
  const float *lin_h_W2, *lin_c_W2, *lin_a_W2;
  const u16 *x_emb, *wp_e0, *wp_e1, *wp_e2, *wp_dc0, *wp_d1, *wp_d2;
  const float *dc_b0p;
  const u16 *w1h, *w1c, *w1a, *demb16;
  const float *bias2d;
  u16 *h_all, *hzero;
  float *enc_c;
  u16 *l0out0, *l0out1, *l1out0, *l1out1;
  u16 *tmp6hc, *eo2, *dec_h0, *dec_h1;
  float *dec_c, *pctx0, *pctx1;
  u16 *bufA, *bufB, *bufC, *embctx;
  float *out, *attn_out;
  int *flags, *release;
};

__global__ __launch_bounds__(256, 1) void mega_kernel(MegaArgs a){
  __shared__ __align__(16) char smem[58368];
  int ep=0;
  int bid=blockIdx.x, tid=threadIdx.x;
  int tfv = a.tf[0];
  u16* l0out[2]={a.l0out0,a.l0out1};
  u16* l1out[2]={a.l1out0,a.l1out1};
  u16* dec_h[2]={a.dec_h0,a.dec_h1};
  float* pctx[2]={a.pctx0,a.pctx1};

  // -------- encoder wavefront: 34 phases --------
  for (int p=0; p<TIN+2; p++){
    for (int l=0; l<3; l++){
      int t=p-l;
      if (t<0 || t>=TIN) continue;
      const u16* hR6 = (t==0)? a.hzero : a.h_all + (size_t)(t-1)*DD*BH;
      u16* hW6 = a.h_all + (size_t)t*DD*BH;
      if (l==0)
        stage_unit<512,0>(a.x_emb+(size_t)t*BB*256, a.wp_e0, a.enc_b,
            hR6,hW6,a.enc_c, l0out[t&1], 0, nullptr,0,nullptr,nullptr,nullptr, smem);
      else if (l==1)
        stage_unit<768,1>(l0out[t&1], a.wp_e1, a.enc_b+2048,
            hR6,hW6,a.enc_c, l1out[t&1], 1, nullptr,0,nullptr,nullptr,nullptr, smem);
      else
        stage_unit<768,1>(l1out[t&1], a.wp_e2, a.enc_b+4096,
            hR6,hW6,a.enc_c, nullptr, 2, nullptr,0,nullptr,nullptr,nullptr, smem);
    }
    gbar(a.flags,a.release,ep);
  }
  // -------- B1: W2 mixes --------
  {
    float* sW2=(float*)smem;    // 108 f
    if (tid<108){
      int pp=tid/36, jj=tid%36;
      const float* src=(pp==0)?a.lin_h_W2:(pp==1?a.lin_c_W2:a.lin_a_W2);
      sW2[tid]=src[jj];
    }
    __syncthreads();
    int half=tid>>7, pr=tid&127, b=bid, hc0=2*pr;
    float v0[6],v1[6];
    if (half==1){
      // h31 mix -> tmp6hc rows [0..1536)
      #pragma unroll
      for (int l2=0;l2<6;l2++){
        u32 hp=ld_sc1((const u32*)(a.h_all+((size_t)(31*6+l2)*BB+b)*256+hc0));
        v0[l2]=bf2f((u16)hp); v1[l2]=bf2f((u16)(hp>>16));
      }
      #pragma unroll
      for (int m=0;m<6;m++){
        float o0=0.f,o1=0.f;
        #pragma unroll
        for (int l2=0;l2<6;l2++){o0+=sW2[m*6+l2]*v0[l2];o1+=sW2[m*6+l2]*v1[l2];}
        st_sc1((u32*)(a.tmp6hc+((size_t)(m*256+b))*256+hc0),(u32)f2bf(o0)|((u32)f2bf(o1)<<16));
      }
    } else {
      // c mix -> tmp6hc rows [1536..3072)
      #pragma unroll
      for (int l2=0;l2<6;l2++){
        v0[l2]=ldf_sc1(a.enc_c+(size_t)l2*BH+(size_t)b*256+hc0);
        v1[l2]=ldf_sc1(a.enc_c+(size_t)l2*BH+(size_t)b*256+hc0+1);
      }
      #pragma unroll
      for (int m=0;m<6;m++){
        float o0=0.f,o1=0.f;
        #pragma unroll
        for (int l2=0;l2<6;l2++){o0+=sW2[36+m*6+l2]*v0[l2];o1+=sW2[36+m*6+l2]*v1[l2];}
        st_sc1((u32*)(a.tmp6hc+((size_t)(1536+m*256+b))*256+hc0),(u32)f2bf(o0)|((u32)f2bf(o1)<<16));
      }
    }
    __syncthreads();    // h31 read before in-place t=31 overwrite below
    for (int t=half*16; t<half*16+16; t++){
      #pragma unroll
      for (int l2=0;l2<6;l2++){
        u32 hp=ld_sc1((const u32*)(a.h_all+((size_t)(t*6+l2)*BB+b)*256+hc0));
        v0[l2]=bf2f((u16)hp); v1[l2]=bf2f((u16)(hp>>16));
      }
      #pragma unroll
      for (int m=0;m<6;m++){
        float o0=0.f,o1=0.f;
        #pragma unroll
        for (int l2=0;l2<6;l2++){o0+=sW2[72+m*6+l2]*v0[l2];o1+=sW2[72+m*6+l2]*v1[l2];}
        st_sc1((u32*)(a.h_all+((size_t)(t*6+m)*BB+b)*256+hc0),(u32)f2bf(o0)|((u32)f2bf(o1)<<16));
      }
    }
  }
  gbar(a.flags,a.release,ep);
  // -------- B2: bridges + attention projection --------
  for (int u=bid; u<6528; u+=NB){
    if (u<192){
      gemm_unit(a.tmp6hc, a.w1h, a.bias2d+1536, (u>>2)*32, (u&3)*64, 0, a.dec_h0, nullptr, smem);
    } else if (u<384){
      int v2=u-192;
      gemm_unit(a.tmp6hc+(size_t)1536*256, a.w1c, a.bias2d+3072, (v2>>2)*32, (v2&3)*64, 1, nullptr, a.dec_c, smem);
    } else {
      int at=u-384;
      gemm_unit(a.h_all, a.w1a, a.bias2d, (at>>2)*32, (at&3)*64, 2, a.eo2, nullptr, smem);
    }
  }
  gbar(a.flags,a.release,ep);
  __threadfence();   // one-time: drop stale L2 lines so eo2 normal reads are fresh
  if (tfv){
    // -------- B3: initial ctx partials from bridge h --------
    {
      int b=bid, hc=tid;
      float acc=0.f;
      for (int d=0;d<6;d++){
        float hv=bf2f(half_sc1(a.dec_h0+(size_t)d*BH+(size_t)b*256+hc, hc&1));
        const u16* eb=a.eo2+((size_t)(b*6+d)*32)*256+hc;
        float se=0.f,ac=0.f;
        #pragma unroll 8
        for (int t=0;t<TIN;t++){float ev=bf2f(eb[t*256]);float e=expf(hv*ev);se+=e;ac+=e*ev;}
        acc+=ac/se;
      }
      stf_sc1(a.pctx0+(size_t)b*256+hc, acc);
    }
    gbar(a.flags,a.release,ep);
    // -------- decoder (teacher-forced): 3 phases/step --------
    for (int i=0;i<TOUT-1;i++){
      if (i>0) fc_fold(a.bufC, a.fc_W, a.fc_b, a.out, i, nullptr, smem);
      stage_unit<768,2>(a.demb16, a.wp_dc0, a.dc_b0p,
          dec_h[i&1], dec_h[(i+1)&1], a.dec_c, a.bufA, 0,
          a.target, i, pctx[i&1], pctx[(i+1)&1], a.eo2, smem);
      gbar(a.flags,a.release,ep);
      stf_sc1(pctx[i&1]+(size_t)bid*256+tid, 0.f);     // recycle for step i+2
      stage_unit<768,1>(a.bufA, a.wp_d1, a.dec_b+2048,
          dec_h[i&1], dec_h[(i+1)&1], a.dec_c, a.bufB, 1,
          nullptr,0,nullptr, pctx[(i+1)&1], a.eo2, smem);
      gbar(a.flags,a.release,ep);
      stage_unit<768,1>(a.bufB, a.wp_d2, a.dec_b+4096,
          dec_h[i&1], dec_h[(i+1)&1], a.dec_c, a.bufC, 2,
          nullptr,0,nullptr, pctx[(i+1)&1], a.eo2, smem);
      gbar(a.flags,a.release,ep);
    }
    fc_fold(a.bufC, a.fc_W, a.fc_b, a.out, TOUT-1, nullptr, smem);
  } else {
    // -------- decoder (free-running): 4 phases/step --------
    for (int i=0;i<TOUT-1;i++){
      {
        float* lg=(float*)(smem+2688);
        int* tokp=(int*)(smem+3072);
        if (i>0) fc_fold(a.bufC, a.fc_W, a.fc_b, a.out, i, lg, smem);
        if (tid==0){
          int tok=1;
          if (i>0){ tok=0; float bv=lg[0];
            for (int v=1;v<VDEC;v++){float x=lg[v];if(x>bv){bv=x;tok=v;}} }
          *tokp=tok;
        }
        __syncthreads();
        int tok=*tokp, b=bid;
        if (tid<128)
          st_sc1((u32*)(a.embctx+(size_t)b*512)+tid, *((const u32*)(a.demb16+(size_t)tok*256)+tid));
        int hc=tid;
        float acc=0.f;
        for (int d=0;d<6;d++){
          float hv=bf2f(half_sc1(dec_h[i&1]+(size_t)d*BH+(size_t)b*256+hc, hc&1));
          const u16* eb=a.eo2+((size_t)(b*6+d)*32)*256+hc;
          float se=0.f,ac=0.f;
          #pragma unroll 8
          for (int t=0;t<TIN;t++){float ev=bf2f(eb[t*256]);float e=expf(hv*ev);se+=e;ac+=e*ev;}
          acc+=ac/se;
          float inv=1.f/se;
          for (int t=0;t<TIN;t++){
            float ev=bf2f(eb[t*256]);
            atomicAdd(&a.attn_out[(((size_t)(i+1)*TIN+t)*DD+d)*BB+b], expf(hv*ev)*inv);
          }
        }
        u16 cb=f2bf(acc*(1.f/6.f));
        u32 other=(u32)__shfl_xor((int)(u32)cb,1,64);
        if (!(hc&1))
          st_sc1((u32*)(a.embctx+(size_t)b*512+256+hc),(u32)cb|(other<<16));
      }
      gbar(a.flags,a.release,ep);
      stage_unit<768,1>(a.embctx, a.wp_dc0, a.dc_b0p,
          dec_h[i&1], dec_h[(i+1)&1], a.dec_c, a.bufA, 0,
          nullptr,0,nullptr,nullptr,nullptr, smem);
      gbar(a.flags,a.release,ep);
      stage_unit<768,1>(a.bufA, a.wp_d1, a.dec_b+2048,
          dec_h[i&1], dec_h[(i+1)&1], a.dec_c, a.bufB, 1,
          nullptr,0,nullptr,nullptr,nullptr, smem);
      gbar(a.flags,a.release,ep);
      stage_unit<768,1>(a.bufB, a.wp_d2, a.dec_b+4096,
          dec_h[i&1], dec_h[(i+1)&1], a.dec_c, a.bufC, 2,
          nullptr,0,nullptr,nullptr,nullptr, smem);
      gbar(a.flags,a.release,ep);
    }
    fc_fold(a.bufC, a.fc_W, a.fc_b, a.out, TOUT-1, nullptr, smem);
  }
}

// =====================================================================

extern "C" void kernel_launch(void* const* d_in, const int* in_sizes, int n_in,
                              void* d_out, int out_size, void* d_ws, size_t ws_size,
                              hipStream_t stream){
  (void)in_sizes; (void)n_in; (void)out_size; (void)ws_size;
  const int*   input    = (const int*)d_in[0];
  const int*   target   = (const int*)d_in[1];
  const int*   tf       = (const int*)d_in[2];
  const float* enc_emb  = (const float*)d_in[3];
  const float* dec_emb  = (const float*)d_in[4];
  const float* enc_Wih0 = (const float*)d_in[5];
  const float* enc_Wih1 = (const float*)d_in[6];
  const float* enc_Whh  = (const float*)d_in[7];
  const float* enc_b    = (const float*)d_in[8];
  const float* dec_Wih0 = (const float*)d_in[9];
  const float* dec_Wih1 = (const float*)d_in[10];
  const float* dec_Whh  = (const float*)d_in[11];
  const float* dec_b    = (const float*)d_in[12];
  const float* lin_h_W1 = (const float*)d_in[13];
  const float* lin_h_b1 = (const float*)d_in[14];
  const float* lin_h_W2 = (const float*)d_in[15];
  const float* lin_h_b2 = (const float*)d_in[16];
  const float* lin_c_W1 = (const float*)d_in[17];
  const float* lin_c_b1 = (const float*)d_in[18];
  const float* lin_c_W2 = (const float*)d_in[19];
  const float* lin_c_b2 = (const float*)d_in[20];
  const float* lin_a_W1 = (const float*)d_in[21];
  const float* lin_a_b1 = (const float*)d_in[22];
  const float* lin_a_W2 = (const float*)d_in[23];
  const float* lin_a_b2 = (const float*)d_in[24];
  const float* attn_W   = (const float*)d_in[25];
  const float* attn_b   = (const float*)d_in[26];
  const float* fc_W     = (const float*)d_in[27];
  const float* fc_b     = (const float*)d_in[28];
  float* out = (float*)d_out;

  char* base=(char*)d_ws;
  size_t off=0;
  auto alloc=[&](size_t bytes)->char*{
    char* p=base+off; off=(off+bytes+255)&~(size_t)255; return p;
  };
  // ---- zero region (contiguous): flags | release | hzero | enc_c | pctx0 | pctx1 ----
  int*   flags  =(int*)  alloc(sizeof(int)*256*16);               // 16384
  int*   release=(int*)  alloc(256);                              // 256
  u16*   hzero  =(u16*)  alloc(sizeof(u16)*(size_t)DD*BH);        // 786432
  float* enc_c  =(float*)alloc(sizeof(float)*(size_t)DD*BH);      // 1572864
  float* pctx0  =(float*)alloc(sizeof(float)*(size_t)BB*256);     // 262144
  float* pctx1  =(float*)alloc(sizeof(float)*(size_t)BB*256);     // 262144
  int zero_n = (16384+256+786432+1572864+262144+262144)/4;

  u16*   dec_h0 =(u16*)  alloc(sizeof(u16)*(size_t)DD*BH);
  u16*   dec_h1 =(u16*)  alloc(sizeof(u16)*(size_t)DD*BH);
  float* dec_c  =(float*)alloc(sizeof(float)*(size_t)DD*BH);
  u16*   tmp6hc =(u16*)  alloc(sizeof(u16)*(size_t)2*1536*256);
  u16*   h_all  =(u16*)  alloc(sizeof(u16)*(size_t)TIN*DD*BH);
  u16*   eo2    =(u16*)  alloc(sizeof(u16)*(size_t)TIN*DD*BH);
  u16*   x_emb  =(u16*)  alloc(sizeof(u16)*(size_t)TIN*BB*EDIM);
  u16*   l0out0 =(u16*)  alloc(sizeof(u16)*(size_t)BB*512);
  u16*   l0out1 =(u16*)  alloc(sizeof(u16)*(size_t)BB*512);
  u16*   l1out0 =(u16*)  alloc(sizeof(u16)*(size_t)BB*512);
  u16*   l1out1 =(u16*)  alloc(sizeof(u16)*(size_t)BB*512);
  u16*   bufA   =(u16*)  alloc(sizeof(u16)*(size_t)BB*512);
  u16*   bufB   =(u16*)  alloc(sizeof(u16)*(size_t)BB*512);
  u16*   bufC   =(u16*)  alloc(sizeof(u16)*(size_t)BB*512);
  u16*   embctx =(u16*)  alloc(sizeof(u16)*(size_t)BB*512);
  float* bias2d =(float*)alloc(sizeof(float)*3*6*256);
  float* dc_b0p =(float*)alloc(sizeof(float)*2048);
  u16*   w1h    =(u16*)  alloc(sizeof(u16)*65536);
  u16*   w1c    =(u16*)  alloc(sizeof(u16)*65536);
  u16*   w1a    =(u16*)  alloc(sizeof(u16)*65536);
  u16*   demb16 =(u16*)  alloc(sizeof(u16)*VDEC*256);
  u16*   wp_e0  =(u16*)  alloc(sizeof(u16)*(size_t)2048*512);
  u16*   wp_e1  =(u16*)  alloc(sizeof(u16)*(size_t)2048*768);
  u16*   wp_e2  =(u16*)  alloc(sizeof(u16)*(size_t)2048*768);
  u16*   wp_dc0 =(u16*)  alloc(sizeof(u16)*(size_t)2048*768);
  u16*   wp_d1  =(u16*)  alloc(sizeof(u16)*(size_t)2048*768);
  u16*   wp_d2  =(u16*)  alloc(sizeof(u16)*(size_t)2048*768);

  const int out_n = TOUT*BB*VDEC + TOUT*TIN*DD*BB;
  int zb = (zero_n+255)/256;
  int ob = (out_n+255)/256;
  int total_blocks = 4096 + 6144*4 + 256 + 72 + 256 + 1 + 8192 + zb + ob;

  SetupArgs s;
  s.enc_Wih0=enc_Wih0; s.enc_Wih1=enc_Wih1; s.enc_Whh=enc_Whh; s.enc_b=enc_b;
  s.dec_Wih0=dec_Wih0; s.dec_Wih1=dec_Wih1; s.dec_Whh=dec_Whh; s.dec_b=dec_b;
  s.lin_h_W1=lin_h_W1; s.lin_c_W1=lin_c_W1; s.lin_a_W1=lin_a_W1;
  s.dec_emb=dec_emb; s.enc_emb=enc_emb;
  s.attn_W=attn_W; s.attn_b=attn_b;
  s.aW2=lin_a_W2; s.ab1=lin_a_b1; s.ab2=lin_a_b2;
  s.hW2=lin_h_W2; s.hb1=lin_h_b1; s.hb2=lin_h_b2;
  s.cW2=lin_c_W2; s.cb1=lin_c_b1; s.cb2=lin_c_b2;
  s.input=input;
  s.wp_e0=wp_e0; s.wp_e1=wp_e1; s.wp_e2=wp_e2; s.wp_d1=wp_d1; s.wp_d2=wp_d2; s.wp_dc0=wp_dc0;
  s.w1h=w1h; s.w1c=w1c; s.w1a=w1a; s.demb16=demb16; s.x_emb=x_emb;
  s.bias2d=bias2d; s.dc_b0p=dc_b0p;
  s.zero_ptr=(u32*)flags; s.zero_n=zero_n;
  s.out=out; s.out_n=out_n;
  setup_kernel<<<total_blocks, 256, 0, stream>>>(s);

  MegaArgs a;
  a.target=target; a.tf=tf;
  a.enc_b=enc_b; a.dec_b=dec_b; a.fc_W=fc_W; a.fc_b=fc_b;
  a.lin_h_W2=lin_h_W2; a.lin_c_W2=lin_c_W2; a.lin_a_W2=lin_a_W2;
  a.x_emb=x_emb; a.wp_e0=wp_e0; a.wp_e1=wp_e1; a.wp_e2=wp_e2;
  a.wp_dc0=wp_dc0; a.wp_d1=wp_d1; a.wp_d2=wp_d2;
  a.dc_b0p=dc_b0p; a.w1h=w1h; a.w1c=w1c; a.w1a=w1a; a.demb16=demb16;
  a.bias2d=bias2d;
  a.h_all=h_all; a.hzero=hzero; a.enc_c=enc_c;
  a.l0out0=l0out0; a.l0out1=l0out1; a.l1out0=l1out0; a.l1out1=l1out1;
  a.tmp6hc=tmp6hc; a.eo2=eo2; a.dec_h0=dec_h0; a.dec_h1=dec_h1;
  a.dec_c=dec_c; a.pctx0=pctx0; a.pctx1=pctx1;
  a.bufA=bufA; a.bufB=bufB; a.bufC=bufC; a.embctx=embctx;
  a.out=out; a.attn_out=out+(size_t)TOUT*BB*VDEC;
  a.flags=flags; a.release=release;
  mega_kernel<<<NB, 256, 0, stream>>>(a);
}